// Round 15
// baseline (1027.634 us; speedup 1.0000x reference)
//
#include <hip/hip_runtime.h>
#include <hip/hip_bf16.h>

#define T_TOK 8192
#define D_DIM 1024
#define F_DIM 4096
#define E_NUM 8
#define BM 128
#define MAX_ROWS (2 * T_TOK + E_NUM * BM)   // 17408
#define NUM_RB (MAX_ROWS / BM)              // 136

typedef __hip_bfloat16 bf16;
using bf16x8  = __attribute__((ext_vector_type(8))) __bf16;
using float4v = __attribute__((ext_vector_type(4))) float;

// async global->LDS, 16B per lane; dest = wave-uniform base + lane*16
__device__ inline void gl_lds16(const bf16* g, bf16* l) {
    __builtin_amdgcn_global_load_lds(
        (const __attribute__((address_space(1))) void*)g,
        (__attribute__((address_space(3))) void*)l, 16, 0, 0);
}

// Barrier-free per-wave phase: wait own vmcnt (prev buffer landed), ds_read
// own frags, lgkmcnt(0) (reads in regs) then re-stage the buffer, then MFMA
// covers the DMA flight. NO s_barrier anywhere in the K-loop.
#define PHW(VMSTR, AR, BR, DOSTAGE, KST, BUF)                                  \
    do {                                                                       \
        asm volatile("s_waitcnt " VMSTR ::: "memory");                         \
        bf16x8 af[4], bfr[4];                                                  \
        _Pragma("unroll")                                                      \
        for (int m_ = 0; m_ < 4; ++m_)                                         \
            af[m_] = *(const bf16x8*)&(AR)[(m_ * 16 + fr) * 32 + fkk];         \
        _Pragma("unroll")                                                      \
        for (int n_ = 0; n_ < 4; ++n_)                                         \
            bfr[n_] = *(const bf16x8*)&(BR)[(n_ * 16 + fr) * 32 + fkk];        \
        asm volatile("s_waitcnt lgkmcnt(0)" ::: "memory");                     \
        if (DOSTAGE) stage(KST, BUF);                                          \
        __builtin_amdgcn_s_setprio(1);                                         \
        _Pragma("unroll")                                                      \
        for (int m_ = 0; m_ < 4; ++m_)                                         \
            _Pragma("unroll")                                                  \
            for (int n_ = 0; n_ < 4; ++n_)                                     \
                acc[m_][n_] = __builtin_amdgcn_mfma_f32_16x16x32_bf16(         \
                    af[m_], bfr[n_], acc[m_][n_], 0, 0, 0);                    \
        __builtin_amdgcn_s_setprio(0);                                         \
    } while (0)

// ---- fused transpose+convert for BOTH weights in one dispatch ----
__global__ __launch_bounds__(256) void transpose_both(
    const float* __restrict__ W1, bf16* __restrict__ W1t,
    const float* __restrict__ W2, bf16* __restrict__ W2t) {
    __shared__ float tile[64][65];
    const int flat = blockIdx.x;
    const float* s;
    bf16* d;
    int M, N, n0, m0;
    if (flat < 8192) {
        const int e = flat >> 10, rem = flat & 1023;
        M = D_DIM; N = F_DIM;
        n0 = (rem & 63) * 64; m0 = (rem >> 6) * 64;
        s = W1 + (size_t)e * M * N;
        d = W1t + (size_t)e * M * N;
    } else {
        const int f2 = flat - 8192;
        const int e = f2 >> 10, rem = f2 & 1023;
        M = F_DIM; N = D_DIM;
        n0 = (rem & 15) * 64; m0 = (rem >> 4) * 64;
        s = W2 + (size_t)e * M * N;
        d = W2t + (size_t)e * M * N;
    }
    const int tx = threadIdx.x & 15, ty = threadIdx.x >> 4;
#pragma unroll
    for (int i = 0; i < 4; ++i) {
        const int r = ty + i * 16;
        const float4 v = *(const float4*)&s[(size_t)(m0 + r) * N + n0 + tx * 4];
        tile[r][tx * 4 + 0] = v.x;
        tile[r][tx * 4 + 1] = v.y;
        tile[r][tx * 4 + 2] = v.z;
        tile[r][tx * 4 + 3] = v.w;
    }
    __syncthreads();
#pragma unroll
    for (int i = 0; i < 4; ++i) {
        const int nc = ty + i * 16;
        bf16 o[4];
#pragma unroll
        for (int j = 0; j < 4; ++j) o[j] = __float2bfloat16(tile[tx * 4 + j][nc]);
        *(ushort4*)&d[(size_t)(n0 + nc) * M + m0 + tx * 4] = *(const ushort4*)o;
    }
}

// ---- router + x->bf16 fused ----
__global__ __launch_bounds__(256) void router_xcvt_kernel(
    const float* __restrict__ x, const float* __restrict__ Wg,
    const float* __restrict__ bg, int* __restrict__ top_idx,
    float* __restrict__ top_gate, int* __restrict__ counts,
    bf16* __restrict__ xb) {
    __shared__ float wg_s[E_NUM][D_DIM];
    for (int i = threadIdx.x; i < D_DIM * E_NUM; i += 256)
        wg_s[i & 7][i >> 3] = Wg[i];
    __syncthreads();

    const int lane = threadIdx.x & 63;
    const int t = blockIdx.x * 4 + (threadIdx.x >> 6);
    float acc[E_NUM];
#pragma unroll
    for (int e = 0; e < E_NUM; ++e) acc[e] = 0.f;
    const float* xrow = x + (size_t)t * D_DIM;
    for (int d = lane; d < D_DIM; d += 64) {
        const float xv = xrow[d];
#pragma unroll
        for (int e = 0; e < E_NUM; ++e) acc[e] += xv * wg_s[e][d];
    }
#pragma unroll
    for (int off = 32; off > 0; off >>= 1) {
#pragma unroll
        for (int e = 0; e < E_NUM; ++e) acc[e] += __shfl_xor(acc[e], off, 64);
    }
    if (lane == 0) {
        float v[E_NUM];
#pragma unroll
        for (int e = 0; e < E_NUM; ++e) v[e] = acc[e] + bg[e];
        int i0 = 0;
#pragma unroll
        for (int e = 1; e < E_NUM; ++e)
            if (v[e] > v[i0]) i0 = e;
        int i1 = -1;
#pragma unroll
        for (int e = 0; e < E_NUM; ++e) {
            if (e == i0) continue;
            if (i1 < 0 || v[e] > v[i1]) i1 = e;
        }
        const float g0 = 1.f / (1.f + expf(v[i1] - v[i0]));
        top_idx[2 * t] = i0;
        top_idx[2 * t + 1] = i1;
        top_gate[2 * t] = g0;
        top_gate[2 * t + 1] = 1.f - g0;
        atomicAdd(&counts[i0], 1);
        atomicAdd(&counts[i1], 1);
    }
    const float4* xs = (const float4*)(x + (size_t)blockIdx.x * 4 * D_DIM);
    ushort4* xd = (ushort4*)(xb + (size_t)blockIdx.x * 4 * D_DIM);
    for (int i = threadIdx.x; i < D_DIM; i += 256) {
        float4 v = xs[i];
        bf16 tmp[4];
        tmp[0] = __float2bfloat16(v.x);
        tmp[1] = __float2bfloat16(v.y);
        tmp[2] = __float2bfloat16(v.z);
        tmp[3] = __float2bfloat16(v.w);
        xd[i] = *(const ushort4*)tmp;
    }
}

// ---- scatter with inline offsets ----
__global__ __launch_bounds__(256) void scatter_kernel(
    const int* __restrict__ top_idx, const float* __restrict__ top_gate,
    const int* __restrict__ counts, int* __restrict__ offsets,
    int* __restrict__ cursors, int* __restrict__ tok_list,
    float* __restrict__ gate_list) {
    int offs[E_NUM + 1];
    int o = 0;
#pragma unroll
    for (int e = 0; e < E_NUM; ++e) {
        offs[e] = o;
        o += (counts[e] + BM - 1) / BM * BM;
    }
    offs[E_NUM] = o;
    if (blockIdx.x == 0 && threadIdx.x < E_NUM + 1) offsets[threadIdx.x] = offs[threadIdx.x];

    const int t = blockIdx.x * 256 + threadIdx.x;
    if (t >= T_TOK) return;
#pragma unroll
    for (int j = 0; j < 2; ++j) {
        const int e = top_idx[2 * t + j];
        const int pos = atomicAdd(&cursors[e], 1);
        const int slot = offs[e] + pos;
        tok_list[slot] = t;
        gate_list[slot] = top_gate[2 * t + j];
    }
}

// ---------------- GEMM1: barrier-free per-wave-private LDS pipeline ----------
// 128x128 block = 4 waves x (64x64). Each wave stages ITS OWN A-rows and
// B-cols into private LDS (2-buffer), waits only on its own vmcnt.
__global__ __launch_bounds__(256, 2) void gemm1_kernel(
    const bf16* __restrict__ xb, const bf16* __restrict__ W1t,
    const float* __restrict__ b1, const int* __restrict__ tok_list,
    const int* __restrict__ offsets, bf16* __restrict__ hbuf) {
    __shared__ bf16 AsAll[4 * 2 * 2048];   // [wave][buf][64*32]
    __shared__ bf16 BsAll[4 * 2 * 2048];
    __shared__ int toks[BM];

    const int NCB = F_DIM / 128;          // 32
    const int per = (NUM_RB * NCB) / 8;   // 544
    const int flat = blockIdx.x;
    const int sw = (flat & 7) * per + (flat >> 3);
    const int rb = sw / NCB, cb = sw % NCB;

    const int row0 = rb * BM;
    const int total = offsets[E_NUM];
    if (row0 >= total) return;
    int e = 0;
#pragma unroll
    for (int i = 1; i < E_NUM; ++i) e += (row0 >= offsets[i]) ? 1 : 0;

    const int tid = threadIdx.x;
    if (tid < BM) toks[tid] = tok_list[row0 + tid];
    __syncthreads();   // drains toks loads; the ONLY block barrier

    const int lane = tid & 63;
    const int w = tid >> 6;
    const int f0 = cb * 128;
    const int wrow = (w >> 1) * 64, wcol = (w & 1) * 64;

    // per-wave staging: issue i covers local row i*16 + (lane>>2), chunk lane&3
    const int sr = lane >> 2;
    const int c16 = (lane & 3) ^ ((lane >> 3) & 3);   // T2 pre-swizzled source
    const bf16* aP[4];
    const bf16* bP[4];
#pragma unroll
    for (int i = 0; i < 4; ++i) {
        int t = toks[wrow + i * 16 + sr];
        if (t < 0) t = 0;
        aP[i] = xb + (size_t)t * D_DIM + c16 * 8;
        bP[i] = W1t + ((size_t)e * F_DIM + f0 + wcol + i * 16 + sr) * D_DIM + c16 * 8;
    }

    const unsigned wbase = __builtin_amdgcn_readfirstlane(w * 8192);  // bytes
    bf16* Ar0 = (bf16*)((char*)AsAll + wbase);
    bf16* Ar1 = (bf16*)((char*)AsAll + wbase + 4096);
    bf16* Br0 = (bf16*)((char*)BsAll + wbase);
    bf16* Br1 = (bf16*)((char*)BsAll + wbase + 4096);

    const int fr = lane & 15;
    const int fkk = 8 * ((lane >> 4) ^ ((lane >> 1) & 3));

    float4v acc[4][4];
#pragma unroll
    for (int m = 0; m < 4; ++m)
#pragma unroll
        for (int n = 0; n < 4; ++n)
#pragma unroll
            for (int r = 0; r < 4; ++r) acc[m][n][r] = 0.f;

    auto stage = [&](int kt, int buf) {
        const int ko = kt * 32;
        char* Ab = (char*)AsAll + wbase + buf * 4096;
        char* Bb = (char*)BsAll + wbase + buf * 4096;
#pragma unroll
        for (int i = 0; i < 4; ++i) {
            gl_lds16(aP[i] + ko, (bf16*)(Ab + i * 1024));
            gl_lds16(bP[i] + ko, (bf16*)(Bb + i * 1024));
        }
    };

    const int NKT = D_DIM / 32;  // 32, even
    stage(0, 0);
    stage(1, 1);
    for (int kt = 0; kt < NKT - 2; kt += 2) {
        PHW("vmcnt(8)", Ar0, Br0, true, kt + 2, 0);
        PHW("vmcnt(8)", Ar1, Br1, true, kt + 3, 1);
    }
    PHW("vmcnt(8)", Ar0, Br0, false, 0, 0);
    PHW("vmcnt(0)", Ar1, Br1, false, 0, 1);

#pragma unroll
    for (int n = 0; n < 4; ++n) {
        const int gcol = f0 + wcol + n * 16 + fr;
        const float bias = b1[e * F_DIM + gcol];
#pragma unroll
        for (int m = 0; m < 4; ++m) {
#pragma unroll
            for (int r = 0; r < 4; ++r) {
                const int grow = row0 + wrow + m * 16 + (lane >> 4) * 4 + r;
                float v = acc[m][n][r] + bias;
                v = fmaxf(v, 0.f);
                hbuf[(size_t)grow * F_DIM + gcol] = __float2bfloat16(v);
            }
        }
    }
}

// ---------------- GEMM2: barrier-free per-wave pipeline, scatter-add ----------
__global__ __launch_bounds__(256, 2) void gemm2_kernel(
    const bf16* __restrict__ hbuf, const bf16* __restrict__ W2t,
    const float* __restrict__ b2, const int* __restrict__ tok_list,
    const float* __restrict__ gate_list, const int* __restrict__ offsets,
    float* __restrict__ out) {
    __shared__ bf16 AsAll[4 * 2 * 2048];
    __shared__ bf16 BsAll[4 * 2 * 2048];
    __shared__ int toks[BM];
    __shared__ float gates_s[BM];

    const int NCB = D_DIM / 128;          // 8
    const int per = (NUM_RB * NCB) / 8;   // 136
    const int flat = blockIdx.x;
    const int sw = (flat & 7) * per + (flat >> 3);
    const int rb = sw / NCB, cb = sw % NCB;

    const int row0 = rb * BM;
    const int total = offsets[E_NUM];
    if (row0 >= total) return;
    int e = 0;
#pragma unroll
    for (int i = 1; i < E_NUM; ++i) e += (row0 >= offsets[i]) ? 1 : 0;

    const int tid = threadIdx.x;
    if (tid < BM) {
        int t = tok_list[row0 + tid];
        toks[tid] = t;
        gates_s[tid] = (t >= 0) ? gate_list[row0 + tid] : 0.f;
    }
    __syncthreads();

    const int lane = tid & 63;
    const int w = tid >> 6;
    const int d0 = cb * 128;
    const int wrow = (w >> 1) * 64, wcol = (w & 1) * 64;

    const int sr = lane >> 2;
    const int c16 = (lane & 3) ^ ((lane >> 3) & 3);
    const bf16* aP[4];
    const bf16* bP[4];
#pragma unroll
    for (int i = 0; i < 4; ++i) {
        aP[i] = hbuf + (size_t)(row0 + wrow + i * 16 + sr) * F_DIM + c16 * 8;
        bP[i] = W2t + ((size_t)e * D_DIM + d0 + wcol + i * 16 + sr) * F_DIM + c16 * 8;
    }

    const unsigned wbase = __builtin_amdgcn_readfirstlane(w * 8192);
    bf16* Ar0 = (bf16*)((char*)AsAll + wbase);
    bf16* Ar1 = (bf16*)((char*)AsAll + wbase + 4096);
    bf16* Br0 = (bf16*)((char*)BsAll + wbase);
    bf16* Br1 = (bf16*)((char*)BsAll + wbase + 4096);

    const int fr = lane & 15;
    const int fkk = 8 * ((lane >> 4) ^ ((lane >> 1) & 3));

    float4v acc[4][4];
#pragma unroll
    for (int m = 0; m < 4; ++m)
#pragma unroll
        for (int n = 0; n < 4; ++n)
#pragma unroll
            for (int r = 0; r < 4; ++r) acc[m][n][r] = 0.f;

    auto stage = [&](int kt, int buf) {
        const int ko = kt * 32;
        char* Ab = (char*)AsAll + wbase + buf * 4096;
        char* Bb = (char*)BsAll + wbase + buf * 4096;
#pragma unroll
        for (int i = 0; i < 4; ++i) {
            gl_lds16(aP[i] + ko, (bf16*)(Ab + i * 1024));
            gl_lds16(bP[i] + ko, (bf16*)(Bb + i * 1024));
        }
    };

    const int NKT = F_DIM / 32;  // 128, even
    stage(0, 0);
    stage(1, 1);
    for (int kt = 0; kt < NKT - 2; kt += 2) {
        PHW("vmcnt(8)", Ar0, Br0, true, kt + 2, 0);
        PHW("vmcnt(8)", Ar1, Br1, true, kt + 3, 1);
    }
    PHW("vmcnt(8)", Ar0, Br0, false, 0, 0);
    PHW("vmcnt(0)", Ar1, Br1, false, 0, 1);

#pragma unroll
    for (int n = 0; n < 4; ++n) {
        const int gcol = d0 + wcol + n * 16 + fr;
        const float bias = b2[e * D_DIM + gcol];
#pragma unroll
        for (int m = 0; m < 4; ++m) {
#pragma unroll
            for (int r = 0; r < 4; ++r) {
                const int lrow = wrow + m * 16 + (lane >> 4) * 4 + r;
                const int t = toks[lrow];
                if (t >= 0) {
                    const float v = (acc[m][n][r] + bias) * gates_s[lrow];
                    atomicAdd(&out[(size_t)t * D_DIM + gcol], v);
                }
            }
        }
    }
}

extern "C" void kernel_launch(void* const* d_in, const int* in_sizes, int n_in,
                              void* d_out, int out_size, void* d_ws, size_t ws_size,
                              hipStream_t stream) {
    const float* x = (const float*)d_in[0];
    const float* Wg = (const float*)d_in[1];
    const float* bg = (const float*)d_in[2];
    const float* W1 = (const float*)d_in[3];
    const float* b1 = (const float*)d_in[4];
    const float* W2 = (const float*)d_in[5];
    const float* b2 = (const float*)d_in[6];
    float* out = (float*)d_out;

    char* ws = (char*)d_ws;
    int* counts = (int*)(ws + 0);       // 8 ints
    int* cursors = (int*)(ws + 32);     // 8 ints
    int* offsets = (int*)(ws + 64);     // 9 ints
    int* top_idx = (int*)(ws + 256);                     // T*2 ints
    float* top_gate = (float*)(ws + 256 + 65536);        // T*2 floats
    int* tok_list = (int*)(ws + 256 + 2 * 65536);        // MAX_ROWS ints
    float* gate_list = (float*)(ws + 256 + 2 * 65536 + 69632);
    size_t off = 256 + 2 * 65536 + 2 * 69632;            // 270592, 256-aligned
    bf16* xb = (bf16*)(ws + off);
    off += (size_t)T_TOK * D_DIM * 2;
    bf16* W1t = (bf16*)(ws + off);
    off += (size_t)E_NUM * D_DIM * F_DIM * 2;
    bf16* W2t = (bf16*)(ws + off);
    off += (size_t)E_NUM * D_DIM * F_DIM * 2;
    bf16* hbuf = (bf16*)(ws + off);

    hipMemsetAsync(d_out, 0, (size_t)T_TOK * D_DIM * sizeof(float), stream);
    hipMemsetAsync(ws, 0, 64, stream);                       // counts + cursors
    hipMemsetAsync(tok_list, 0xFF, (size_t)MAX_ROWS * 4, stream);  // -1 sentinels

    transpose_both<<<16384, 256, 0, stream>>>(W1, W1t, W2, W2t);
    router_xcvt_kernel<<<T_TOK / 4, 256, 0, stream>>>(x, Wg, bg, top_idx, top_gate,
                                                      counts, xb);
    scatter_kernel<<<T_TOK / 256, 256, 0, stream>>>(top_idx, top_gate, counts, offsets,
                                                    cursors, tok_list, gate_list);
    gemm1_kernel<<<NUM_RB * (F_DIM / 128), 256, 0, stream>>>(xb, W1t, b1, tok_list,
                                                             offsets, hbuf);
    gemm2_kernel<<<NUM_RB * (D_DIM / 128), 256, 0, stream>>>(hbuf, W2t, b2, tok_list,
                                                             gate_list, offsets, out);
}

// Round 16
// 847.888 us; speedup vs baseline: 1.2120x; 1.2120x over previous
//
#include <hip/hip_runtime.h>
#include <hip/hip_bf16.h>

#define T_TOK 8192
#define D_DIM 1024
#define F_DIM 4096
#define HB_F  2048                           // F-half processed per pass
#define E_NUM 8
#define BM 128
#define MAX_ROWS (2 * T_TOK + E_NUM * BM)   // 17408
#define NUM_RB (MAX_ROWS / BM)              // 136

typedef __hip_bfloat16 bf16;
using bf16x8  = __attribute__((ext_vector_type(8))) __bf16;
using float4v = __attribute__((ext_vector_type(4))) float;

// async global->LDS, 16B per lane; dest = uniform base + lane*16
__device__ inline void gl_lds16(const bf16* g, bf16* l) {
    __builtin_amdgcn_global_load_lds(
        (const __attribute__((address_space(1))) void*)g,
        (__attribute__((address_space(3))) void*)l, 16, 0, 0);
}

// R4 phase: counted vmcnt, pinned reads, 2 barriers, stage after 2nd barrier.
#define PH(WAITSTR, CA, CB, DOSTAGE, KST)                                      \
    do {                                                                       \
        asm volatile("s_waitcnt " WAITSTR ::: "memory");                       \
        __builtin_amdgcn_s_barrier();                                          \
        bf16x8 af[4], bfr[4];                                                  \
        _Pragma("unroll")                                                      \
        for (int m_ = 0; m_ < 4; ++m_)                                         \
            af[m_] = *(const bf16x8*)&(CA)[(wrow + m_ * 16 + fr) * 32 + fkk];  \
        _Pragma("unroll")                                                      \
        for (int n_ = 0; n_ < 4; ++n_)                                         \
            bfr[n_] = *(const bf16x8*)&(CB)[(wcol + n_ * 16 + fr) * 32 + fkk]; \
        asm volatile("s_waitcnt lgkmcnt(0)" ::: "memory");                     \
        __builtin_amdgcn_sched_barrier(0);                                     \
        __builtin_amdgcn_s_barrier();                                          \
        if (DOSTAGE) stage(KST, CA, CB);                                       \
        __builtin_amdgcn_s_setprio(1);                                         \
        _Pragma("unroll")                                                      \
        for (int m_ = 0; m_ < 4; ++m_)                                         \
            _Pragma("unroll")                                                  \
            for (int n_ = 0; n_ < 4; ++n_)                                     \
                acc[m_][n_] = __builtin_amdgcn_mfma_f32_16x16x32_bf16(         \
                    af[m_], bfr[n_], acc[m_][n_], 0, 0, 0);                    \
        __builtin_amdgcn_s_setprio(0);                                         \
    } while (0)

// ---- transpose+convert: src[e][M][N] f32 -> dst[e][N][M] bf16, 64x64 tiles,
// restricted to an (n_off, m_off) window so halves can be produced just-in-time.
__global__ __launch_bounds__(256) void transpose_cvt(
    const float* __restrict__ src, bf16* __restrict__ dst,
    int M, int N, int n_off, int m_off) {
    __shared__ float tile[64][65];
    const int e = blockIdx.z;
    const float* s = src + (size_t)e * M * N;
    bf16* d = dst + (size_t)e * M * N;
    const int n0 = n_off + blockIdx.x * 64, m0 = m_off + blockIdx.y * 64;
    const int tx = threadIdx.x & 15, ty = threadIdx.x >> 4;
#pragma unroll
    for (int i = 0; i < 4; ++i) {
        const int r = ty + i * 16;
        const float4 v = *(const float4*)&s[(size_t)(m0 + r) * N + n0 + tx * 4];
        tile[r][tx * 4 + 0] = v.x;
        tile[r][tx * 4 + 1] = v.y;
        tile[r][tx * 4 + 2] = v.z;
        tile[r][tx * 4 + 3] = v.w;
    }
    __syncthreads();
#pragma unroll
    for (int i = 0; i < 4; ++i) {
        const int nc = ty + i * 16;
        bf16 o[4];
#pragma unroll
        for (int j = 0; j < 4; ++j) o[j] = __float2bfloat16(tile[tx * 4 + j][nc]);
        *(ushort4*)&d[(size_t)(n0 + nc) * M + m0 + tx * 4] = *(const ushort4*)o;
    }
}

// ---- router + x->bf16 fused ----
__global__ __launch_bounds__(256) void router_xcvt_kernel(
    const float* __restrict__ x, const float* __restrict__ Wg,
    const float* __restrict__ bg, int* __restrict__ top_idx,
    float* __restrict__ top_gate, int* __restrict__ counts,
    bf16* __restrict__ xb) {
    __shared__ float wg_s[E_NUM][D_DIM];
    for (int i = threadIdx.x; i < D_DIM * E_NUM; i += 256)
        wg_s[i & 7][i >> 3] = Wg[i];
    __syncthreads();

    const int lane = threadIdx.x & 63;
    const int t = blockIdx.x * 4 + (threadIdx.x >> 6);
    float acc[E_NUM];
#pragma unroll
    for (int e = 0; e < E_NUM; ++e) acc[e] = 0.f;
    const float* xrow = x + (size_t)t * D_DIM;
    for (int d = lane; d < D_DIM; d += 64) {
        const float xv = xrow[d];
#pragma unroll
        for (int e = 0; e < E_NUM; ++e) acc[e] += xv * wg_s[e][d];
    }
#pragma unroll
    for (int off = 32; off > 0; off >>= 1) {
#pragma unroll
        for (int e = 0; e < E_NUM; ++e) acc[e] += __shfl_xor(acc[e], off, 64);
    }
    if (lane == 0) {
        float v[E_NUM];
#pragma unroll
        for (int e = 0; e < E_NUM; ++e) v[e] = acc[e] + bg[e];
        int i0 = 0;
#pragma unroll
        for (int e = 1; e < E_NUM; ++e)
            if (v[e] > v[i0]) i0 = e;
        int i1 = -1;
#pragma unroll
        for (int e = 0; e < E_NUM; ++e) {
            if (e == i0) continue;
            if (i1 < 0 || v[e] > v[i1]) i1 = e;
        }
        const float g0 = 1.f / (1.f + expf(v[i1] - v[i0]));
        top_idx[2 * t] = i0;
        top_idx[2 * t + 1] = i1;
        top_gate[2 * t] = g0;
        top_gate[2 * t + 1] = 1.f - g0;
        atomicAdd(&counts[i0], 1);
        atomicAdd(&counts[i1], 1);
    }
    const float4* xs = (const float4*)(x + (size_t)blockIdx.x * 4 * D_DIM);
    ushort4* xd = (ushort4*)(xb + (size_t)blockIdx.x * 4 * D_DIM);
    for (int i = threadIdx.x; i < D_DIM; i += 256) {
        float4 v = xs[i];
        bf16 tmp[4];
        tmp[0] = __float2bfloat16(v.x);
        tmp[1] = __float2bfloat16(v.y);
        tmp[2] = __float2bfloat16(v.z);
        tmp[3] = __float2bfloat16(v.w);
        xd[i] = *(const ushort4*)tmp;
    }
}

// ---- scatter with inline offsets ----
__global__ __launch_bounds__(256) void scatter_kernel(
    const int* __restrict__ top_idx, const float* __restrict__ top_gate,
    const int* __restrict__ counts, int* __restrict__ offsets,
    int* __restrict__ cursors, int* __restrict__ tok_list,
    float* __restrict__ gate_list) {
    int offs[E_NUM + 1];
    int o = 0;
#pragma unroll
    for (int e = 0; e < E_NUM; ++e) {
        offs[e] = o;
        o += (counts[e] + BM - 1) / BM * BM;
    }
    offs[E_NUM] = o;
    if (blockIdx.x == 0 && threadIdx.x < E_NUM + 1) offsets[threadIdx.x] = offs[threadIdx.x];

    const int t = blockIdx.x * 256 + threadIdx.x;
    if (t >= T_TOK) return;
#pragma unroll
    for (int j = 0; j < 2; ++j) {
        const int e = top_idx[2 * t + j];
        const int pos = atomicAdd(&cursors[e], 1);
        const int slot = offs[e] + pos;
        tok_list[slot] = t;
        gate_list[slot] = top_gate[2 * t + j];
    }
}

// ---------------- GEMM1 (R4 schedule): h-half = relu(gather(x)@W1[:,half]) ---
// fHalf selects the F-window; hbuf holds only the current half [rows][HB_F].
__global__ __launch_bounds__(256, 4) void gemm1_kernel(
    const bf16* __restrict__ xb, const bf16* __restrict__ W1t,
    const float* __restrict__ b1, const int* __restrict__ tok_list,
    const int* __restrict__ offsets, bf16* __restrict__ hbuf, int fHalf) {
    __shared__ bf16 As0[BM * 32];
    __shared__ bf16 As1[BM * 32];
    __shared__ bf16 Bs0[BM * 32];
    __shared__ bf16 Bs1[BM * 32];
    __shared__ int toks[BM];

    const int NCB = HB_F / 128;           // 16
    const int per = (NUM_RB * NCB) / 8;   // 272
    const int flat = blockIdx.x;
    const int sw = (flat & 7) * per + (flat >> 3);
    const int rb = sw / NCB, cb = sw % NCB;

    const int row0 = rb * BM;
    const int total = offsets[E_NUM];
    if (row0 >= total) return;
    int e = 0;
#pragma unroll
    for (int i = 1; i < E_NUM; ++i) e += (row0 >= offsets[i]) ? 1 : 0;

    const int tid = threadIdx.x;
    if (tid < BM) toks[tid] = tok_list[row0 + tid];
    __syncthreads();   // full drain: vmcnt henceforth counts only stage loads

    const int lane = tid & 63;
    const int w = tid >> 6;
    const int f0 = cb * 128;              // within the half

    const int r0 = w * 16 + (lane >> 2);
    const int r1 = 64 + w * 16 + (lane >> 2);
    const int c16 = (lane & 3) ^ ((lane >> 3) & 3);
    int t0 = toks[r0]; if (t0 < 0) t0 = 0;
    int t1 = toks[r1]; if (t1 < 0) t1 = 0;
    const bf16* aP0 = xb + (size_t)t0 * D_DIM + c16 * 8;
    const bf16* aP1 = xb + (size_t)t1 * D_DIM + c16 * 8;
    const bf16* bP0 = W1t + ((size_t)e * F_DIM + fHalf + f0 + r0) * D_DIM + c16 * 8;
    const bf16* bP1 = W1t + ((size_t)e * F_DIM + fHalf + f0 + r1) * D_DIM + c16 * 8;

    const unsigned dO0 = __builtin_amdgcn_readfirstlane(w * 1024);
    const unsigned dO1 = __builtin_amdgcn_readfirstlane(4096 + w * 1024);

    const int wrow = (w >> 1) * 64, wcol = (w & 1) * 64;
    const int fr = lane & 15;
    const int fkk = 8 * ((lane >> 4) ^ ((lane >> 1) & 3));

    float4v acc[4][4];
#pragma unroll
    for (int m = 0; m < 4; ++m)
#pragma unroll
        for (int n = 0; n < 4; ++n)
#pragma unroll
            for (int r = 0; r < 4; ++r) acc[m][n][r] = 0.f;

    auto stage = [&](int kt, bf16* A, bf16* B) {
        const int ko = kt * 32;
        gl_lds16(aP0 + ko, (bf16*)((char*)A + dO0));
        gl_lds16(aP1 + ko, (bf16*)((char*)A + dO1));
        gl_lds16(bP0 + ko, (bf16*)((char*)B + dO0));
        gl_lds16(bP1 + ko, (bf16*)((char*)B + dO1));
    };

    const int NKT = D_DIM / 32;  // 32 (K = D is unchanged by the F-split)
    stage(0, As0, Bs0);
    stage(1, As1, Bs1);
    for (int kt = 0; kt < NKT - 2; kt += 2) {
        PH("vmcnt(4)", As0, Bs0, true, kt + 2);
        PH("vmcnt(4)", As1, Bs1, true, kt + 3);
    }
    PH("vmcnt(4)", As0, Bs0, false, 0);
    PH("vmcnt(0)", As1, Bs1, false, 0);

#pragma unroll
    for (int n = 0; n < 4; ++n) {
        const int gcol = f0 + wcol + n * 16 + fr;              // within half
        const float bias = b1[e * F_DIM + fHalf + gcol];
#pragma unroll
        for (int m = 0; m < 4; ++m) {
#pragma unroll
            for (int r = 0; r < 4; ++r) {
                const int grow = row0 + wrow + m * 16 + (lane >> 4) * 4 + r;
                float v = acc[m][n][r] + bias;
                v = fmaxf(v, 0.f);
                hbuf[(size_t)grow * HB_F + gcol] = __float2bfloat16(v);
            }
        }
    }
}

// ---------------- GEMM2 (R4 schedule): out += gate*(h_half @ W2[half,:]) -----
__global__ __launch_bounds__(256, 4) void gemm2_kernel(
    const bf16* __restrict__ hbuf, const bf16* __restrict__ W2t,
    const float* __restrict__ b2, const int* __restrict__ tok_list,
    const float* __restrict__ gate_list, const int* __restrict__ offsets,
    float* __restrict__ out, int fHalf, int doBias) {
    __shared__ bf16 As0[BM * 32];
    __shared__ bf16 As1[BM * 32];
    __shared__ bf16 Bs0[BM * 32];
    __shared__ bf16 Bs1[BM * 32];
    __shared__ int toks[BM];
    __shared__ float gates_s[BM];

    const int NCB = D_DIM / 128;          // 8
    const int per = (NUM_RB * NCB) / 8;   // 136
    const int flat = blockIdx.x;
    const int sw = (flat & 7) * per + (flat >> 3);
    const int rb = sw / NCB, cb = sw % NCB;

    const int row0 = rb * BM;
    const int total = offsets[E_NUM];
    if (row0 >= total) return;
    int e = 0;
#pragma unroll
    for (int i = 1; i < E_NUM; ++i) e += (row0 >= offsets[i]) ? 1 : 0;

    const int tid = threadIdx.x;
    if (tid < BM) {
        int t = tok_list[row0 + tid];
        toks[tid] = t;
        gates_s[tid] = (t >= 0) ? gate_list[row0 + tid] : 0.f;
    }
    __syncthreads();

    const int lane = tid & 63;
    const int w = tid >> 6;
    const int d0 = cb * 128;

    const int r0 = w * 16 + (lane >> 2);
    const int r1 = 64 + w * 16 + (lane >> 2);
    const int c16 = (lane & 3) ^ ((lane >> 3) & 3);
    const bf16* aP0 = hbuf + (size_t)(row0 + r0) * HB_F + c16 * 8;
    const bf16* aP1 = hbuf + (size_t)(row0 + r1) * HB_F + c16 * 8;
    const bf16* bP0 = W2t + ((size_t)e * D_DIM + d0 + r0) * F_DIM + fHalf + c16 * 8;
    const bf16* bP1 = W2t + ((size_t)e * D_DIM + d0 + r1) * F_DIM + fHalf + c16 * 8;

    const unsigned dO0 = __builtin_amdgcn_readfirstlane(w * 1024);
    const unsigned dO1 = __builtin_amdgcn_readfirstlane(4096 + w * 1024);

    const int wrow = (w >> 1) * 64, wcol = (w & 1) * 64;
    const int fr = lane & 15;
    const int fkk = 8 * ((lane >> 4) ^ ((lane >> 1) & 3));

    float4v acc[4][4];
#pragma unroll
    for (int m = 0; m < 4; ++m)
#pragma unroll
        for (int n = 0; n < 4; ++n)
#pragma unroll
            for (int r = 0; r < 4; ++r) acc[m][n][r] = 0.f;

    auto stage = [&](int kt, bf16* A, bf16* B) {
        const int ko = kt * 32;
        gl_lds16(aP0 + ko, (bf16*)((char*)A + dO0));
        gl_lds16(aP1 + ko, (bf16*)((char*)A + dO1));
        gl_lds16(bP0 + ko, (bf16*)((char*)B + dO0));
        gl_lds16(bP1 + ko, (bf16*)((char*)B + dO1));
    };

    const int NKT = HB_F / 32;  // 64
    stage(0, As0, Bs0);
    stage(1, As1, Bs1);
    for (int kt = 0; kt < NKT - 2; kt += 2) {
        PH("vmcnt(4)", As0, Bs0, true, kt + 2);
        PH("vmcnt(4)", As1, Bs1, true, kt + 3);
    }
    PH("vmcnt(4)", As0, Bs0, false, 0);
    PH("vmcnt(0)", As1, Bs1, false, 0);

#pragma unroll
    for (int n = 0; n < 4; ++n) {
        const int gcol = d0 + wcol + n * 16 + fr;
        const float bias = doBias ? b2[e * D_DIM + gcol] : 0.f;
#pragma unroll
        for (int m = 0; m < 4; ++m) {
#pragma unroll
            for (int r = 0; r < 4; ++r) {
                const int lrow = wrow + m * 16 + (lane >> 4) * 4 + r;
                const int t = toks[lrow];
                if (t >= 0) {
                    const float v = (acc[m][n][r] + bias) * gates_s[lrow];
                    atomicAdd(&out[(size_t)t * D_DIM + gcol], v);
                }
            }
        }
    }
}

extern "C" void kernel_launch(void* const* d_in, const int* in_sizes, int n_in,
                              void* d_out, int out_size, void* d_ws, size_t ws_size,
                              hipStream_t stream) {
    const float* x = (const float*)d_in[0];
    const float* Wg = (const float*)d_in[1];
    const float* bg = (const float*)d_in[2];
    const float* W1 = (const float*)d_in[3];
    const float* b1 = (const float*)d_in[4];
    const float* W2 = (const float*)d_in[5];
    const float* b2 = (const float*)d_in[6];
    float* out = (float*)d_out;

    char* ws = (char*)d_ws;
    int* counts = (int*)(ws + 0);       // 8 ints
    int* cursors = (int*)(ws + 32);     // 8 ints
    int* offsets = (int*)(ws + 64);     // 9 ints
    int* top_idx = (int*)(ws + 256);                     // T*2 ints
    float* top_gate = (float*)(ws + 256 + 65536);        // T*2 floats
    int* tok_list = (int*)(ws + 256 + 2 * 65536);        // MAX_ROWS ints
    float* gate_list = (float*)(ws + 256 + 2 * 65536 + 69632);
    size_t off = 256 + 2 * 65536 + 2 * 69632;            // 270592, 256-aligned
    bf16* xb = (bf16*)(ws + off);
    off += (size_t)T_TOK * D_DIM * 2;
    bf16* W1t = (bf16*)(ws + off);
    off += (size_t)E_NUM * D_DIM * F_DIM * 2;
    bf16* W2t = (bf16*)(ws + off);
    off += (size_t)E_NUM * D_DIM * F_DIM * 2;
    bf16* hbuf = (bf16*)(ws + off);                      // [MAX_ROWS][HB_F]

    hipMemsetAsync(d_out, 0, (size_t)T_TOK * D_DIM * sizeof(float), stream);
    hipMemsetAsync(ws, 0, 64, stream);                       // counts + cursors
    hipMemsetAsync(tok_list, 0xFF, (size_t)MAX_ROWS * 4, stream);  // -1 sentinels

    // Half-interleaved pipeline: every consumer reads data written within the
    // last ~100-150 MB of traffic so it is still L3-resident.
    router_xcvt_kernel<<<T_TOK / 4, 256, 0, stream>>>(x, Wg, bg, top_idx, top_gate,
                                                      counts, xb);
    scatter_kernel<<<T_TOK / 256, 256, 0, stream>>>(top_idx, top_gate, counts, offsets,
                                                    cursors, tok_list, gate_list);
    for (int h = 0; h < 2; ++h) {
        const int fHalf = h * HB_F;
        // W1t columns [fHalf, fHalf+HB_F): transpose window n_off = fHalf
        transpose_cvt<<<dim3(HB_F / 64, D_DIM / 64, E_NUM), 256, 0, stream>>>(
            W1, W1t, D_DIM, F_DIM, fHalf, 0);
        gemm1_kernel<<<NUM_RB * (HB_F / 128), 256, 0, stream>>>(
            xb, W1t, b1, tok_list, offsets, hbuf, fHalf);
        // W2t k-window [fHalf, fHalf+HB_F): transpose window m_off = fHalf
        transpose_cvt<<<dim3(D_DIM / 64, HB_F / 64, E_NUM), 256, 0, stream>>>(
            W2, W2t, F_DIM, D_DIM, 0, fHalf);
        gemm2_kernel<<<NUM_RB * (D_DIM / 128), 256, 0, stream>>>(
            hbuf, W2t, b2, tok_list, gate_list, offsets, out, fHalf, h == 0);
    }
}

// Round 17
// 798.842 us; speedup vs baseline: 1.2864x; 1.0614x over previous
//
#include <hip/hip_runtime.h>
#include <hip/hip_bf16.h>

#define T_TOK 8192
#define D_DIM 1024
#define F_DIM 4096
#define E_NUM 8
#define BM 128
#define MAX_ROWS (2 * T_TOK + E_NUM * BM)   // 17408
#define NUM_RB (MAX_ROWS / BM)              // 136

typedef __hip_bfloat16 bf16;
using bf16x8  = __attribute__((ext_vector_type(8))) __bf16;
using float4v = __attribute__((ext_vector_type(4))) float;

// async global->LDS, 16B per lane; dest = uniform base + lane*16
__device__ inline void gl_lds16(const bf16* g, bf16* l) {
    __builtin_amdgcn_global_load_lds(
        (const __attribute__((address_space(1))) void*)g,
        (__attribute__((address_space(3))) void*)l, 16, 0, 0);
}

// R4 phase: counted vmcnt, pinned reads, 2 barriers, stage after 2nd barrier.
#define PH(WAITSTR, CA, CB, DOSTAGE, KST)                                      \
    do {                                                                       \
        asm volatile("s_waitcnt " WAITSTR ::: "memory");                       \
        __builtin_amdgcn_s_barrier();                                          \
        bf16x8 af[4], bfr[4];                                                  \
        _Pragma("unroll")                                                      \
        for (int m_ = 0; m_ < 4; ++m_)                                         \
            af[m_] = *(const bf16x8*)&(CA)[(wrow + m_ * 16 + fr) * 32 + fkk];  \
        _Pragma("unroll")                                                      \
        for (int n_ = 0; n_ < 4; ++n_)                                         \
            bfr[n_] = *(const bf16x8*)&(CB)[(wcol + n_ * 16 + fr) * 32 + fkk]; \
        asm volatile("s_waitcnt lgkmcnt(0)" ::: "memory");                     \
        __builtin_amdgcn_sched_barrier(0);                                     \
        __builtin_amdgcn_s_barrier();                                          \
        if (DOSTAGE) stage(KST, CA, CB);                                       \
        __builtin_amdgcn_s_setprio(1);                                         \
        _Pragma("unroll")                                                      \
        for (int m_ = 0; m_ < 4; ++m_)                                         \
            _Pragma("unroll")                                                  \
            for (int n_ = 0; n_ < 4; ++n_)                                     \
                acc[m_][n_] = __builtin_amdgcn_mfma_f32_16x16x32_bf16(         \
                    af[m_], bfr[n_], acc[m_][n_], 0, 0, 0);                    \
        __builtin_amdgcn_s_setprio(0);                                         \
    } while (0)

// ---- fused transpose+convert for BOTH weights in one dispatch ----
__global__ __launch_bounds__(256) void transpose_both(
    const float* __restrict__ W1, bf16* __restrict__ W1t,
    const float* __restrict__ W2, bf16* __restrict__ W2t) {
    __shared__ float tile[64][65];
    const int flat = blockIdx.x;
    const float* s;
    bf16* d;
    int M, N, n0, m0;
    if (flat < 8192) {
        const int e = flat >> 10, rem = flat & 1023;
        M = D_DIM; N = F_DIM;
        n0 = (rem & 63) * 64; m0 = (rem >> 6) * 64;
        s = W1 + (size_t)e * M * N;
        d = W1t + (size_t)e * M * N;
    } else {
        const int f2 = flat - 8192;
        const int e = f2 >> 10, rem = f2 & 1023;
        M = F_DIM; N = D_DIM;
        n0 = (rem & 15) * 64; m0 = (rem >> 4) * 64;
        s = W2 + (size_t)e * M * N;
        d = W2t + (size_t)e * M * N;
    }
    const int tx = threadIdx.x & 15, ty = threadIdx.x >> 4;
#pragma unroll
    for (int i = 0; i < 4; ++i) {
        const int r = ty + i * 16;
        const float4 v = *(const float4*)&s[(size_t)(m0 + r) * N + n0 + tx * 4];
        tile[r][tx * 4 + 0] = v.x;
        tile[r][tx * 4 + 1] = v.y;
        tile[r][tx * 4 + 2] = v.z;
        tile[r][tx * 4 + 3] = v.w;
    }
    __syncthreads();
#pragma unroll
    for (int i = 0; i < 4; ++i) {
        const int nc = ty + i * 16;
        bf16 o[4];
#pragma unroll
        for (int j = 0; j < 4; ++j) o[j] = __float2bfloat16(tile[tx * 4 + j][nc]);
        *(ushort4*)&d[(size_t)(n0 + nc) * M + m0 + tx * 4] = *(const ushort4*)o;
    }
}

// ---- router + x->bf16 fused, NO LDS: Wg[d][e] has e contiguous, so each
// lane loads all 8 expert weights for its dim d as two float4 (coalesced,
// L2-resident). Kills the 32KB/block LDS fill + 8-way-conflict stores that
// made the old router 203 us.
__global__ __launch_bounds__(256) void router_xcvt_kernel(
    const float* __restrict__ x, const float* __restrict__ Wg,
    const float* __restrict__ bg, int* __restrict__ top_idx,
    float* __restrict__ top_gate, int* __restrict__ counts,
    bf16* __restrict__ xb) {
    const int lane = threadIdx.x & 63;
    const int t = blockIdx.x * 4 + (threadIdx.x >> 6);
    const float* xrow = x + (size_t)t * D_DIM;

    float acc[E_NUM];
#pragma unroll
    for (int e = 0; e < E_NUM; ++e) acc[e] = 0.f;
#pragma unroll
    for (int it = 0; it < D_DIM / 64; ++it) {   // 16 independent iterations
        const int d = it * 64 + lane;
        const float xv = xrow[d];
        const float4 w0 = *(const float4*)&Wg[d * 8];
        const float4 w1 = *(const float4*)&Wg[d * 8 + 4];
        acc[0] += xv * w0.x; acc[1] += xv * w0.y;
        acc[2] += xv * w0.z; acc[3] += xv * w0.w;
        acc[4] += xv * w1.x; acc[5] += xv * w1.y;
        acc[6] += xv * w1.z; acc[7] += xv * w1.w;
    }
#pragma unroll
    for (int off = 32; off > 0; off >>= 1) {
#pragma unroll
        for (int e = 0; e < E_NUM; ++e) acc[e] += __shfl_xor(acc[e], off, 64);
    }
    if (lane == 0) {
        float v[E_NUM];
#pragma unroll
        for (int e = 0; e < E_NUM; ++e) v[e] = acc[e] + bg[e];
        int i0 = 0;
#pragma unroll
        for (int e = 1; e < E_NUM; ++e)
            if (v[e] > v[i0]) i0 = e;
        int i1 = -1;
#pragma unroll
        for (int e = 0; e < E_NUM; ++e) {
            if (e == i0) continue;
            if (i1 < 0 || v[e] > v[i1]) i1 = e;
        }
        const float g0 = 1.f / (1.f + expf(v[i1] - v[i0]));
        top_idx[2 * t] = i0;
        top_idx[2 * t + 1] = i1;
        top_gate[2 * t] = g0;
        top_gate[2 * t + 1] = 1.f - g0;
        atomicAdd(&counts[i0], 1);
        atomicAdd(&counts[i1], 1);
    }
    // fused x->bf16 for this block's 4 rows (x slab is L2-hot)
    const float4* xs = (const float4*)(x + (size_t)blockIdx.x * 4 * D_DIM);
    ushort4* xd = (ushort4*)(xb + (size_t)blockIdx.x * 4 * D_DIM);
    for (int i = threadIdx.x; i < D_DIM; i += 256) {
        float4 v = xs[i];
        bf16 tmp[4];
        tmp[0] = __float2bfloat16(v.x);
        tmp[1] = __float2bfloat16(v.y);
        tmp[2] = __float2bfloat16(v.z);
        tmp[3] = __float2bfloat16(v.w);
        xd[i] = *(const ushort4*)tmp;
    }
}

// ---- scatter with inline offsets ----
__global__ __launch_bounds__(256) void scatter_kernel(
    const int* __restrict__ top_idx, const float* __restrict__ top_gate,
    const int* __restrict__ counts, int* __restrict__ offsets,
    int* __restrict__ cursors, int* __restrict__ tok_list,
    float* __restrict__ gate_list) {
    int offs[E_NUM + 1];
    int o = 0;
#pragma unroll
    for (int e = 0; e < E_NUM; ++e) {
        offs[e] = o;
        o += (counts[e] + BM - 1) / BM * BM;
    }
    offs[E_NUM] = o;
    if (blockIdx.x == 0 && threadIdx.x < E_NUM + 1) offsets[threadIdx.x] = offs[threadIdx.x];

    const int t = blockIdx.x * 256 + threadIdx.x;
    if (t >= T_TOK) return;
#pragma unroll
    for (int j = 0; j < 2; ++j) {
        const int e = top_idx[2 * t + j];
        const int pos = atomicAdd(&cursors[e], 1);
        const int slot = offs[e] + pos;
        tok_list[slot] = t;
        gate_list[slot] = top_gate[2 * t + j];
    }
}

// ---------------- GEMM1 (exact R4): 128², 2-buf counted vmcnt ----------------
__global__ __launch_bounds__(256, 4) void gemm1_kernel(
    const bf16* __restrict__ xb, const bf16* __restrict__ W1t,
    const float* __restrict__ b1, const int* __restrict__ tok_list,
    const int* __restrict__ offsets, bf16* __restrict__ hbuf) {
    __shared__ bf16 As0[BM * 32];
    __shared__ bf16 As1[BM * 32];
    __shared__ bf16 Bs0[BM * 32];
    __shared__ bf16 Bs1[BM * 32];
    __shared__ int toks[BM];

    const int NCB = F_DIM / 128;          // 32
    const int per = (NUM_RB * NCB) / 8;   // 544
    const int flat = blockIdx.x;
    const int sw = (flat & 7) * per + (flat >> 3);
    const int rb = sw / NCB, cb = sw % NCB;

    const int row0 = rb * BM;
    const int total = offsets[E_NUM];
    if (row0 >= total) return;
    int e = 0;
#pragma unroll
    for (int i = 1; i < E_NUM; ++i) e += (row0 >= offsets[i]) ? 1 : 0;

    const int tid = threadIdx.x;
    if (tid < BM) toks[tid] = tok_list[row0 + tid];
    __syncthreads();   // full drain: vmcnt henceforth counts only stage loads

    const int lane = tid & 63;
    const int w = tid >> 6;
    const int f0 = cb * 128;

    const int r0 = w * 16 + (lane >> 2);
    const int r1 = 64 + w * 16 + (lane >> 2);
    const int c16 = (lane & 3) ^ ((lane >> 3) & 3);
    int t0 = toks[r0]; if (t0 < 0) t0 = 0;
    int t1 = toks[r1]; if (t1 < 0) t1 = 0;
    const bf16* aP0 = xb + (size_t)t0 * D_DIM + c16 * 8;
    const bf16* aP1 = xb + (size_t)t1 * D_DIM + c16 * 8;
    const bf16* bP0 = W1t + ((size_t)e * F_DIM + f0 + r0) * D_DIM + c16 * 8;
    const bf16* bP1 = W1t + ((size_t)e * F_DIM + f0 + r1) * D_DIM + c16 * 8;

    const unsigned dO0 = __builtin_amdgcn_readfirstlane(w * 1024);
    const unsigned dO1 = __builtin_amdgcn_readfirstlane(4096 + w * 1024);

    const int wrow = (w >> 1) * 64, wcol = (w & 1) * 64;
    const int fr = lane & 15;
    const int fkk = 8 * ((lane >> 4) ^ ((lane >> 1) & 3));

    float4v acc[4][4];
#pragma unroll
    for (int m = 0; m < 4; ++m)
#pragma unroll
        for (int n = 0; n < 4; ++n)
#pragma unroll
            for (int r = 0; r < 4; ++r) acc[m][n][r] = 0.f;

    auto stage = [&](int kt, bf16* A, bf16* B) {
        const int ko = kt * 32;
        gl_lds16(aP0 + ko, (bf16*)((char*)A + dO0));
        gl_lds16(aP1 + ko, (bf16*)((char*)A + dO1));
        gl_lds16(bP0 + ko, (bf16*)((char*)B + dO0));
        gl_lds16(bP1 + ko, (bf16*)((char*)B + dO1));
    };

    const int NKT = D_DIM / 32;  // 32
    stage(0, As0, Bs0);
    stage(1, As1, Bs1);
    for (int kt = 0; kt < NKT - 2; kt += 2) {
        PH("vmcnt(4)", As0, Bs0, true, kt + 2);
        PH("vmcnt(4)", As1, Bs1, true, kt + 3);
    }
    PH("vmcnt(4)", As0, Bs0, false, 0);
    PH("vmcnt(0)", As1, Bs1, false, 0);

#pragma unroll
    for (int n = 0; n < 4; ++n) {
        const int gcol = f0 + wcol + n * 16 + fr;
        const float bias = b1[e * F_DIM + gcol];
#pragma unroll
        for (int m = 0; m < 4; ++m) {
#pragma unroll
            for (int r = 0; r < 4; ++r) {
                const int grow = row0 + wrow + m * 16 + (lane >> 4) * 4 + r;
                float v = acc[m][n][r] + bias;
                v = fmaxf(v, 0.f);
                hbuf[(size_t)grow * F_DIM + gcol] = __float2bfloat16(v);
            }
        }
    }
}

// ---------------- GEMM2 (exact R4): 128², 2-buf counted vmcnt ----------------
__global__ __launch_bounds__(256, 4) void gemm2_kernel(
    const bf16* __restrict__ hbuf, const bf16* __restrict__ W2t,
    const float* __restrict__ b2, const int* __restrict__ tok_list,
    const float* __restrict__ gate_list, const int* __restrict__ offsets,
    float* __restrict__ out) {
    __shared__ bf16 As0[BM * 32];
    __shared__ bf16 As1[BM * 32];
    __shared__ bf16 Bs0[BM * 32];
    __shared__ bf16 Bs1[BM * 32];
    __shared__ int toks[BM];
    __shared__ float gates_s[BM];

    const int NCB = D_DIM / 128;          // 8
    const int per = (NUM_RB * NCB) / 8;   // 136
    const int flat = blockIdx.x;
    const int sw = (flat & 7) * per + (flat >> 3);
    const int rb = sw / NCB, cb = sw % NCB;

    const int row0 = rb * BM;
    const int total = offsets[E_NUM];
    if (row0 >= total) return;
    int e = 0;
#pragma unroll
    for (int i = 1; i < E_NUM; ++i) e += (row0 >= offsets[i]) ? 1 : 0;

    const int tid = threadIdx.x;
    if (tid < BM) {
        int t = tok_list[row0 + tid];
        toks[tid] = t;
        gates_s[tid] = (t >= 0) ? gate_list[row0 + tid] : 0.f;
    }
    __syncthreads();

    const int lane = tid & 63;
    const int w = tid >> 6;
    const int d0 = cb * 128;

    const int r0 = w * 16 + (lane >> 2);
    const int r1 = 64 + w * 16 + (lane >> 2);
    const int c16 = (lane & 3) ^ ((lane >> 3) & 3);
    const bf16* aP0 = hbuf + (size_t)(row0 + r0) * F_DIM + c16 * 8;
    const bf16* aP1 = hbuf + (size_t)(row0 + r1) * F_DIM + c16 * 8;
    const bf16* bP0 = W2t + ((size_t)e * D_DIM + d0 + r0) * F_DIM + c16 * 8;
    const bf16* bP1 = W2t + ((size_t)e * D_DIM + d0 + r1) * F_DIM + c16 * 8;

    const unsigned dO0 = __builtin_amdgcn_readfirstlane(w * 1024);
    const unsigned dO1 = __builtin_amdgcn_readfirstlane(4096 + w * 1024);

    const int wrow = (w >> 1) * 64, wcol = (w & 1) * 64;
    const int fr = lane & 15;
    const int fkk = 8 * ((lane >> 4) ^ ((lane >> 1) & 3));

    float4v acc[4][4];
#pragma unroll
    for (int m = 0; m < 4; ++m)
#pragma unroll
        for (int n = 0; n < 4; ++n)
#pragma unroll
            for (int r = 0; r < 4; ++r) acc[m][n][r] = 0.f;

    auto stage = [&](int kt, bf16* A, bf16* B) {
        const int ko = kt * 32;
        gl_lds16(aP0 + ko, (bf16*)((char*)A + dO0));
        gl_lds16(aP1 + ko, (bf16*)((char*)A + dO1));
        gl_lds16(bP0 + ko, (bf16*)((char*)B + dO0));
        gl_lds16(bP1 + ko, (bf16*)((char*)B + dO1));
    };

    const int NKT = F_DIM / 32;  // 128
    stage(0, As0, Bs0);
    stage(1, As1, Bs1);
    for (int kt = 0; kt < NKT - 2; kt += 2) {
        PH("vmcnt(4)", As0, Bs0, true, kt + 2);
        PH("vmcnt(4)", As1, Bs1, true, kt + 3);
    }
    PH("vmcnt(4)", As0, Bs0, false, 0);
    PH("vmcnt(0)", As1, Bs1, false, 0);

#pragma unroll
    for (int n = 0; n < 4; ++n) {
        const int gcol = d0 + wcol + n * 16 + fr;
        const float bias = b2[e * D_DIM + gcol];
#pragma unroll
        for (int m = 0; m < 4; ++m) {
#pragma unroll
            for (int r = 0; r < 4; ++r) {
                const int lrow = wrow + m * 16 + (lane >> 4) * 4 + r;
                const int t = toks[lrow];
                if (t >= 0) {
                    const float v = (acc[m][n][r] + bias) * gates_s[lrow];
                    atomicAdd(&out[(size_t)t * D_DIM + gcol], v);
                }
            }
        }
    }
}

extern "C" void kernel_launch(void* const* d_in, const int* in_sizes, int n_in,
                              void* d_out, int out_size, void* d_ws, size_t ws_size,
                              hipStream_t stream) {
    const float* x = (const float*)d_in[0];
    const float* Wg = (const float*)d_in[1];
    const float* bg = (const float*)d_in[2];
    const float* W1 = (const float*)d_in[3];
    const float* b1 = (const float*)d_in[4];
    const float* W2 = (const float*)d_in[5];
    const float* b2 = (const float*)d_in[6];
    float* out = (float*)d_out;

    char* ws = (char*)d_ws;
    int* counts = (int*)(ws + 0);       // 8 ints
    int* cursors = (int*)(ws + 32);     // 8 ints
    int* offsets = (int*)(ws + 64);     // 9 ints
    int* top_idx = (int*)(ws + 256);                     // T*2 ints
    float* top_gate = (float*)(ws + 256 + 65536);        // T*2 floats
    int* tok_list = (int*)(ws + 256 + 2 * 65536);        // MAX_ROWS ints
    float* gate_list = (float*)(ws + 256 + 2 * 65536 + 69632);
    size_t off = 256 + 2 * 65536 + 2 * 69632;            // 270592, 256-aligned
    bf16* xb = (bf16*)(ws + off);
    off += (size_t)T_TOK * D_DIM * 2;
    bf16* W1t = (bf16*)(ws + off);
    off += (size_t)E_NUM * D_DIM * F_DIM * 2;
    bf16* W2t = (bf16*)(ws + off);
    off += (size_t)E_NUM * D_DIM * F_DIM * 2;
    bf16* hbuf = (bf16*)(ws + off);

    hipMemsetAsync(d_out, 0, (size_t)T_TOK * D_DIM * sizeof(float), stream);
    hipMemsetAsync(ws, 0, 64, stream);                       // counts + cursors
    hipMemsetAsync(tok_list, 0xFF, (size_t)MAX_ROWS * 4, stream);  // -1 sentinels

    transpose_both<<<16384, 256, 0, stream>>>(W1, W1t, W2, W2t);
    router_xcvt_kernel<<<T_TOK / 4, 256, 0, stream>>>(x, Wg, bg, top_idx, top_gate,
                                                      counts, xb);
    scatter_kernel<<<T_TOK / 256, 256, 0, stream>>>(top_idx, top_gate, counts, offsets,
                                                    cursors, tok_list, gate_list);
    gemm1_kernel<<<NUM_RB * (F_DIM / 128), 256, 0, stream>>>(xb, W1t, b1, tok_list,
                                                             offsets, hbuf);
    gemm2_kernel<<<NUM_RB * (D_DIM / 128), 256, 0, stream>>>(hbuf, W2t, b2, tok_list,
                                                             gate_list, offsets, out);
}

// Round 18
// 583.484 us; speedup vs baseline: 1.7612x; 1.3691x over previous
//
#include <hip/hip_runtime.h>
#include <hip/hip_bf16.h>

#define T_TOK 8192
#define D_DIM 1024
#define F_DIM 4096
#define E_NUM 8
#define BM 128
#define MAX_ROWS (2 * T_TOK + E_NUM * BM)   // 17408
#define NUM_RB (MAX_ROWS / BM)              // 136

typedef __hip_bfloat16 bf16;
using bf16x8  = __attribute__((ext_vector_type(8))) __bf16;
using float4v = __attribute__((ext_vector_type(4))) float;

// async global->LDS, 16B per lane; dest = uniform base + lane*16
__device__ inline void gl_lds16(const bf16* g, bf16* l) {
    __builtin_amdgcn_global_load_lds(
        (const __attribute__((address_space(1))) void*)g,
        (__attribute__((address_space(3))) void*)l, 16, 0, 0);
}

// R4 phase: counted vmcnt, pinned reads, 2 barriers, stage after 2nd barrier.
#define PH(WAITSTR, CA, CB, DOSTAGE, KST)                                      \
    do {                                                                       \
        asm volatile("s_waitcnt " WAITSTR ::: "memory");                       \
        __builtin_amdgcn_s_barrier();                                          \
        bf16x8 af[4], bfr[4];                                                  \
        _Pragma("unroll")                                                      \
        for (int m_ = 0; m_ < 4; ++m_)                                         \
            af[m_] = *(const bf16x8*)&(CA)[(wrow + m_ * 16 + fr) * 32 + fkk];  \
        _Pragma("unroll")                                                      \
        for (int n_ = 0; n_ < 4; ++n_)                                         \
            bfr[n_] = *(const bf16x8*)&(CB)[(wcol + n_ * 16 + fr) * 32 + fkk]; \
        asm volatile("s_waitcnt lgkmcnt(0)" ::: "memory");                     \
        __builtin_amdgcn_sched_barrier(0);                                     \
        __builtin_amdgcn_s_barrier();                                          \
        if (DOSTAGE) stage(KST, CA, CB);                                       \
        __builtin_amdgcn_s_setprio(1);                                         \
        _Pragma("unroll")                                                      \
        for (int m_ = 0; m_ < 4; ++m_)                                         \
            _Pragma("unroll")                                                  \
            for (int n_ = 0; n_ < 4; ++n_)                                     \
                acc[m_][n_] = __builtin_amdgcn_mfma_f32_16x16x32_bf16(         \
                    af[m_], bfr[n_], acc[m_][n_], 0, 0, 0);                    \
        __builtin_amdgcn_s_setprio(0);                                         \
    } while (0)

// ---- fused transpose+convert for BOTH weights in one dispatch ----
__global__ __launch_bounds__(256) void transpose_both(
    const float* __restrict__ W1, bf16* __restrict__ W1t,
    const float* __restrict__ W2, bf16* __restrict__ W2t) {
    __shared__ float tile[64][65];
    const int flat = blockIdx.x;
    const float* s;
    bf16* d;
    int M, N, n0, m0;
    if (flat < 8192) {
        const int e = flat >> 10, rem = flat & 1023;
        M = D_DIM; N = F_DIM;
        n0 = (rem & 63) * 64; m0 = (rem >> 6) * 64;
        s = W1 + (size_t)e * M * N;
        d = W1t + (size_t)e * M * N;
    } else {
        const int f2 = flat - 8192;
        const int e = f2 >> 10, rem = f2 & 1023;
        M = F_DIM; N = D_DIM;
        n0 = (rem & 15) * 64; m0 = (rem >> 4) * 64;
        s = W2 + (size_t)e * M * N;
        d = W2t + (size_t)e * M * N;
    }
    const int tx = threadIdx.x & 15, ty = threadIdx.x >> 4;
#pragma unroll
    for (int i = 0; i < 4; ++i) {
        const int r = ty + i * 16;
        const float4 v = *(const float4*)&s[(size_t)(m0 + r) * N + n0 + tx * 4];
        tile[r][tx * 4 + 0] = v.x;
        tile[r][tx * 4 + 1] = v.y;
        tile[r][tx * 4 + 2] = v.z;
        tile[r][tx * 4 + 3] = v.w;
    }
    __syncthreads();
#pragma unroll
    for (int i = 0; i < 4; ++i) {
        const int nc = ty + i * 16;
        bf16 o[4];
#pragma unroll
        for (int j = 0; j < 4; ++j) o[j] = __float2bfloat16(tile[tx * 4 + j][nc]);
        *(ushort4*)&d[(size_t)(n0 + nc) * M + m0 + tx * 4] = *(const ushort4*)o;
    }
}

// ---- router + x->bf16 fused, NO LDS and NO global atomics ----
__global__ __launch_bounds__(256) void router_xcvt_kernel(
    const float* __restrict__ x, const float* __restrict__ Wg,
    const float* __restrict__ bg, int* __restrict__ top_idx,
    float* __restrict__ top_gate, bf16* __restrict__ xb) {
    const int lane = threadIdx.x & 63;
    const int t = blockIdx.x * 4 + (threadIdx.x >> 6);
    const float* xrow = x + (size_t)t * D_DIM;

    float acc[E_NUM];
#pragma unroll
    for (int e = 0; e < E_NUM; ++e) acc[e] = 0.f;
#pragma unroll
    for (int it = 0; it < D_DIM / 64; ++it) {
        const int d = it * 64 + lane;
        const float xv = xrow[d];
        const float4 w0 = *(const float4*)&Wg[d * 8];
        const float4 w1 = *(const float4*)&Wg[d * 8 + 4];
        acc[0] += xv * w0.x; acc[1] += xv * w0.y;
        acc[2] += xv * w0.z; acc[3] += xv * w0.w;
        acc[4] += xv * w1.x; acc[5] += xv * w1.y;
        acc[6] += xv * w1.z; acc[7] += xv * w1.w;
    }
#pragma unroll
    for (int off = 32; off > 0; off >>= 1) {
#pragma unroll
        for (int e = 0; e < E_NUM; ++e) acc[e] += __shfl_xor(acc[e], off, 64);
    }
    if (lane == 0) {
        float v[E_NUM];
#pragma unroll
        for (int e = 0; e < E_NUM; ++e) v[e] = acc[e] + bg[e];
        int i0 = 0;
#pragma unroll
        for (int e = 1; e < E_NUM; ++e)
            if (v[e] > v[i0]) i0 = e;
        int i1 = -1;
#pragma unroll
        for (int e = 0; e < E_NUM; ++e) {
            if (e == i0) continue;
            if (i1 < 0 || v[e] > v[i1]) i1 = e;
        }
        const float g0 = 1.f / (1.f + expf(v[i1] - v[i0]));
        top_idx[2 * t] = i0;
        top_idx[2 * t + 1] = i1;
        top_gate[2 * t] = g0;
        top_gate[2 * t + 1] = 1.f - g0;
    }
    // fused x->bf16 for this block's 4 rows (x slab is L2-hot)
    const float4* xs = (const float4*)(x + (size_t)blockIdx.x * 4 * D_DIM);
    ushort4* xd = (ushort4*)(xb + (size_t)blockIdx.x * 4 * D_DIM);
    for (int i = threadIdx.x; i < D_DIM; i += 256) {
        float4 v = xs[i];
        bf16 tmp[4];
        tmp[0] = __float2bfloat16(v.x);
        tmp[1] = __float2bfloat16(v.y);
        tmp[2] = __float2bfloat16(v.z);
        tmp[3] = __float2bfloat16(v.w);
        xd[i] = *(const ushort4*)tmp;
    }
}

// ---- single-block count + padded-prefix offsets, ZERO atomics ----
// Each thread counts its strided slice into 8 statically-indexed registers,
// wave shfl-reduce, cross-wave via LDS, thread 0 writes offsets.
__global__ __launch_bounds__(256) void count_offsets_kernel(
    const int* __restrict__ top_idx, int* __restrict__ offsets) {
    __shared__ int whist[4][E_NUM];
    int cnt[E_NUM];
#pragma unroll
    for (int e = 0; e < E_NUM; ++e) cnt[e] = 0;
    for (int i = threadIdx.x; i < 2 * T_TOK; i += 256) {
        const int idx = top_idx[i];
#pragma unroll
        for (int e = 0; e < E_NUM; ++e) cnt[e] += (idx == e) ? 1 : 0;
    }
#pragma unroll
    for (int off = 32; off > 0; off >>= 1) {
#pragma unroll
        for (int e = 0; e < E_NUM; ++e) cnt[e] += __shfl_xor(cnt[e], off, 64);
    }
    const int lane = threadIdx.x & 63, w = threadIdx.x >> 6;
    if (lane == 0) {
#pragma unroll
        for (int e = 0; e < E_NUM; ++e) whist[w][e] = cnt[e];
    }
    __syncthreads();
    if (threadIdx.x == 0) {
        int o = 0;
#pragma unroll
        for (int e = 0; e < E_NUM; ++e) {
            const int c = whist[0][e] + whist[1][e] + whist[2][e] + whist[3][e];
            offsets[e] = o;
            o += (c + BM - 1) / BM * BM;
        }
        offsets[E_NUM] = o;
    }
}

// ---- scatter: per-block LDS histogram + ONE range-reservation atomic per
// (block, expert) => 256 global atomics total instead of 16384 on one line.
__global__ __launch_bounds__(256) void scatter_kernel(
    const int* __restrict__ top_idx, const float* __restrict__ top_gate,
    const int* __restrict__ offsets, int* __restrict__ cursors,
    int* __restrict__ tok_list, float* __restrict__ gate_list) {
    __shared__ int lhist[E_NUM];
    __shared__ int lbase[E_NUM];
    if (threadIdx.x < E_NUM) lhist[threadIdx.x] = 0;
    __syncthreads();

    const int t = blockIdx.x * 256 + threadIdx.x;
    int e0 = top_idx[2 * t], e1 = top_idx[2 * t + 1];
    int p0 = atomicAdd(&lhist[e0], 1);
    int p1 = atomicAdd(&lhist[e1], 1);
    __syncthreads();
    if (threadIdx.x < E_NUM)
        lbase[threadIdx.x] = atomicAdd(&cursors[threadIdx.x], lhist[threadIdx.x]);
    __syncthreads();

    const float g0 = top_gate[2 * t], g1 = top_gate[2 * t + 1];
    const int s0 = offsets[e0] + lbase[e0] + p0;
    const int s1 = offsets[e1] + lbase[e1] + p1;
    tok_list[s0] = t;
    gate_list[s0] = g0;
    tok_list[s1] = t;
    gate_list[s1] = g1;
}

// ---------------- GEMM1 (exact R4): 128², 2-buf counted vmcnt ----------------
__global__ __launch_bounds__(256, 4) void gemm1_kernel(
    const bf16* __restrict__ xb, const bf16* __restrict__ W1t,
    const float* __restrict__ b1, const int* __restrict__ tok_list,
    const int* __restrict__ offsets, bf16* __restrict__ hbuf) {
    __shared__ bf16 As0[BM * 32];
    __shared__ bf16 As1[BM * 32];
    __shared__ bf16 Bs0[BM * 32];
    __shared__ bf16 Bs1[BM * 32];
    __shared__ int toks[BM];

    const int NCB = F_DIM / 128;          // 32
    const int per = (NUM_RB * NCB) / 8;   // 544
    const int flat = blockIdx.x;
    const int sw = (flat & 7) * per + (flat >> 3);
    const int rb = sw / NCB, cb = sw % NCB;

    const int row0 = rb * BM;
    const int total = offsets[E_NUM];
    if (row0 >= total) return;
    int e = 0;
#pragma unroll
    for (int i = 1; i < E_NUM; ++i) e += (row0 >= offsets[i]) ? 1 : 0;

    const int tid = threadIdx.x;
    if (tid < BM) toks[tid] = tok_list[row0 + tid];
    __syncthreads();   // full drain: vmcnt henceforth counts only stage loads

    const int lane = tid & 63;
    const int w = tid >> 6;
    const int f0 = cb * 128;

    const int r0 = w * 16 + (lane >> 2);
    const int r1 = 64 + w * 16 + (lane >> 2);
    const int c16 = (lane & 3) ^ ((lane >> 3) & 3);
    int t0 = toks[r0]; if (t0 < 0) t0 = 0;
    int t1 = toks[r1]; if (t1 < 0) t1 = 0;
    const bf16* aP0 = xb + (size_t)t0 * D_DIM + c16 * 8;
    const bf16* aP1 = xb + (size_t)t1 * D_DIM + c16 * 8;
    const bf16* bP0 = W1t + ((size_t)e * F_DIM + f0 + r0) * D_DIM + c16 * 8;
    const bf16* bP1 = W1t + ((size_t)e * F_DIM + f0 + r1) * D_DIM + c16 * 8;

    const unsigned dO0 = __builtin_amdgcn_readfirstlane(w * 1024);
    const unsigned dO1 = __builtin_amdgcn_readfirstlane(4096 + w * 1024);

    const int wrow = (w >> 1) * 64, wcol = (w & 1) * 64;
    const int fr = lane & 15;
    const int fkk = 8 * ((lane >> 4) ^ ((lane >> 1) & 3));

    float4v acc[4][4];
#pragma unroll
    for (int m = 0; m < 4; ++m)
#pragma unroll
        for (int n = 0; n < 4; ++n)
#pragma unroll
            for (int r = 0; r < 4; ++r) acc[m][n][r] = 0.f;

    auto stage = [&](int kt, bf16* A, bf16* B) {
        const int ko = kt * 32;
        gl_lds16(aP0 + ko, (bf16*)((char*)A + dO0));
        gl_lds16(aP1 + ko, (bf16*)((char*)A + dO1));
        gl_lds16(bP0 + ko, (bf16*)((char*)B + dO0));
        gl_lds16(bP1 + ko, (bf16*)((char*)B + dO1));
    };

    const int NKT = D_DIM / 32;  // 32
    stage(0, As0, Bs0);
    stage(1, As1, Bs1);
    for (int kt = 0; kt < NKT - 2; kt += 2) {
        PH("vmcnt(4)", As0, Bs0, true, kt + 2);
        PH("vmcnt(4)", As1, Bs1, true, kt + 3);
    }
    PH("vmcnt(4)", As0, Bs0, false, 0);
    PH("vmcnt(0)", As1, Bs1, false, 0);

#pragma unroll
    for (int n = 0; n < 4; ++n) {
        const int gcol = f0 + wcol + n * 16 + fr;
        const float bias = b1[e * F_DIM + gcol];
#pragma unroll
        for (int m = 0; m < 4; ++m) {
#pragma unroll
            for (int r = 0; r < 4; ++r) {
                const int grow = row0 + wrow + m * 16 + (lane >> 4) * 4 + r;
                float v = acc[m][n][r] + bias;
                v = fmaxf(v, 0.f);
                hbuf[(size_t)grow * F_DIM + gcol] = __float2bfloat16(v);
            }
        }
    }
}

// ---------------- GEMM2 (exact R4): 128², 2-buf counted vmcnt ----------------
__global__ __launch_bounds__(256, 4) void gemm2_kernel(
    const bf16* __restrict__ hbuf, const bf16* __restrict__ W2t,
    const float* __restrict__ b2, const int* __restrict__ tok_list,
    const float* __restrict__ gate_list, const int* __restrict__ offsets,
    float* __restrict__ out) {
    __shared__ bf16 As0[BM * 32];
    __shared__ bf16 As1[BM * 32];
    __shared__ bf16 Bs0[BM * 32];
    __shared__ bf16 Bs1[BM * 32];
    __shared__ int toks[BM];
    __shared__ float gates_s[BM];

    const int NCB = D_DIM / 128;          // 8
    const int per = (NUM_RB * NCB) / 8;   // 136
    const int flat = blockIdx.x;
    const int sw = (flat & 7) * per + (flat >> 3);
    const int rb = sw / NCB, cb = sw % NCB;

    const int row0 = rb * BM;
    const int total = offsets[E_NUM];
    if (row0 >= total) return;
    int e = 0;
#pragma unroll
    for (int i = 1; i < E_NUM; ++i) e += (row0 >= offsets[i]) ? 1 : 0;

    const int tid = threadIdx.x;
    if (tid < BM) {
        int t = tok_list[row0 + tid];
        toks[tid] = t;
        gates_s[tid] = (t >= 0) ? gate_list[row0 + tid] : 0.f;
    }
    __syncthreads();

    const int lane = tid & 63;
    const int w = tid >> 6;
    const int d0 = cb * 128;

    const int r0 = w * 16 + (lane >> 2);
    const int r1 = 64 + w * 16 + (lane >> 2);
    const int c16 = (lane & 3) ^ ((lane >> 3) & 3);
    const bf16* aP0 = hbuf + (size_t)(row0 + r0) * F_DIM + c16 * 8;
    const bf16* aP1 = hbuf + (size_t)(row0 + r1) * F_DIM + c16 * 8;
    const bf16* bP0 = W2t + ((size_t)e * D_DIM + d0 + r0) * F_DIM + c16 * 8;
    const bf16* bP1 = W2t + ((size_t)e * D_DIM + d0 + r1) * F_DIM + c16 * 8;

    const unsigned dO0 = __builtin_amdgcn_readfirstlane(w * 1024);
    const unsigned dO1 = __builtin_amdgcn_readfirstlane(4096 + w * 1024);

    const int wrow = (w >> 1) * 64, wcol = (w & 1) * 64;
    const int fr = lane & 15;
    const int fkk = 8 * ((lane >> 4) ^ ((lane >> 1) & 3));

    float4v acc[4][4];
#pragma unroll
    for (int m = 0; m < 4; ++m)
#pragma unroll
        for (int n = 0; n < 4; ++n)
#pragma unroll
            for (int r = 0; r < 4; ++r) acc[m][n][r] = 0.f;

    auto stage = [&](int kt, bf16* A, bf16* B) {
        const int ko = kt * 32;
        gl_lds16(aP0 + ko, (bf16*)((char*)A + dO0));
        gl_lds16(aP1 + ko, (bf16*)((char*)A + dO1));
        gl_lds16(bP0 + ko, (bf16*)((char*)B + dO0));
        gl_lds16(bP1 + ko, (bf16*)((char*)B + dO1));
    };

    const int NKT = F_DIM / 32;  // 128
    stage(0, As0, Bs0);
    stage(1, As1, Bs1);
    for (int kt = 0; kt < NKT - 2; kt += 2) {
        PH("vmcnt(4)", As0, Bs0, true, kt + 2);
        PH("vmcnt(4)", As1, Bs1, true, kt + 3);
    }
    PH("vmcnt(4)", As0, Bs0, false, 0);
    PH("vmcnt(0)", As1, Bs1, false, 0);

#pragma unroll
    for (int n = 0; n < 4; ++n) {
        const int gcol = d0 + wcol + n * 16 + fr;
        const float bias = b2[e * D_DIM + gcol];
#pragma unroll
        for (int m = 0; m < 4; ++m) {
#pragma unroll
            for (int r = 0; r < 4; ++r) {
                const int lrow = wrow + m * 16 + (lane >> 4) * 4 + r;
                const int t = toks[lrow];
                if (t >= 0) {
                    const float v = (acc[m][n][r] + bias) * gates_s[lrow];
                    atomicAdd(&out[(size_t)t * D_DIM + gcol], v);
                }
            }
        }
    }
}

extern "C" void kernel_launch(void* const* d_in, const int* in_sizes, int n_in,
                              void* d_out, int out_size, void* d_ws, size_t ws_size,
                              hipStream_t stream) {
    const float* x = (const float*)d_in[0];
    const float* Wg = (const float*)d_in[1];
    const float* bg = (const float*)d_in[2];
    const float* W1 = (const float*)d_in[3];
    const float* b1 = (const float*)d_in[4];
    const float* W2 = (const float*)d_in[5];
    const float* b2 = (const float*)d_in[6];
    float* out = (float*)d_out;

    char* ws = (char*)d_ws;
    int* cursors = (int*)(ws + 32);     // 8 ints
    int* offsets = (int*)(ws + 64);     // 9 ints
    int* top_idx = (int*)(ws + 256);                     // T*2 ints
    float* top_gate = (float*)(ws + 256 + 65536);        // T*2 floats
    int* tok_list = (int*)(ws + 256 + 2 * 65536);        // MAX_ROWS ints
    float* gate_list = (float*)(ws + 256 + 2 * 65536 + 69632);
    size_t off = 256 + 2 * 65536 + 2 * 69632;            // 270592, 256-aligned
    bf16* xb = (bf16*)(ws + off);
    off += (size_t)T_TOK * D_DIM * 2;
    bf16* W1t = (bf16*)(ws + off);
    off += (size_t)E_NUM * D_DIM * F_DIM * 2;
    bf16* W2t = (bf16*)(ws + off);
    off += (size_t)E_NUM * D_DIM * F_DIM * 2;
    bf16* hbuf = (bf16*)(ws + off);

    hipMemsetAsync(d_out, 0, (size_t)T_TOK * D_DIM * sizeof(float), stream);
    hipMemsetAsync(ws, 0, 64, stream);                       // cursors (+pad)
    hipMemsetAsync(tok_list, 0xFF, (size_t)MAX_ROWS * 4, stream);  // -1 sentinels

    transpose_both<<<16384, 256, 0, stream>>>(W1, W1t, W2, W2t);
    router_xcvt_kernel<<<T_TOK / 4, 256, 0, stream>>>(x, Wg, bg, top_idx, top_gate, xb);
    count_offsets_kernel<<<1, 256, 0, stream>>>(top_idx, offsets);
    scatter_kernel<<<T_TOK / 256, 256, 0, stream>>>(top_idx, top_gate, offsets, cursors,
                                                    tok_list, gate_list);
    gemm1_kernel<<<NUM_RB * (F_DIM / 128), 256, 0, stream>>>(xb, W1t, b1, tok_list,
                                                             offsets, hbuf);
    gemm2_kernel<<<NUM_RB * (D_DIM / 128), 256, 0, stream>>>(hbuf, W2t, b2, tok_list,
                                                             gate_list, offsets, out);
}

// Round 19
// 528.447 us; speedup vs baseline: 1.9446x; 1.1041x over previous
//
#include <hip/hip_runtime.h>
#include <hip/hip_bf16.h>

#define T_TOK 8192
#define D_DIM 1024
#define F_DIM 4096
#define E_NUM 8
#define BM 128
#define MAX_ROWS (2 * T_TOK + E_NUM * BM)   // 17408
#define NUM_RB (MAX_ROWS / BM)              // 136
#define G1_BLOCKS (NUM_RB * (F_DIM / 128))  // 4352

typedef __hip_bfloat16 bf16;
using bf16x8  = __attribute__((ext_vector_type(8))) __bf16;
using float4v = __attribute__((ext_vector_type(4))) float;

// async global->LDS, 16B per lane; dest = uniform base + lane*16
__device__ inline void gl_lds16(const bf16* g, bf16* l) {
    __builtin_amdgcn_global_load_lds(
        (const __attribute__((address_space(1))) void*)g,
        (__attribute__((address_space(3))) void*)l, 16, 0, 0);
}

// R4 phase: counted vmcnt, pinned reads, 2 barriers, stage after 2nd barrier.
#define PH(WAITSTR, CA, CB, DOSTAGE, KST)                                      \
    do {                                                                       \
        asm volatile("s_waitcnt " WAITSTR ::: "memory");                       \
        __builtin_amdgcn_s_barrier();                                          \
        bf16x8 af[4], bfr[4];                                                  \
        _Pragma("unroll")                                                      \
        for (int m_ = 0; m_ < 4; ++m_)                                         \
            af[m_] = *(const bf16x8*)&(CA)[(wrow + m_ * 16 + fr) * 32 + fkk];  \
        _Pragma("unroll")                                                      \
        for (int n_ = 0; n_ < 4; ++n_)                                         \
            bfr[n_] = *(const bf16x8*)&(CB)[(wcol + n_ * 16 + fr) * 32 + fkk]; \
        asm volatile("s_waitcnt lgkmcnt(0)" ::: "memory");                     \
        __builtin_amdgcn_sched_barrier(0);                                     \
        __builtin_amdgcn_s_barrier();                                          \
        if (DOSTAGE) stage(KST, CA, CB);                                       \
        __builtin_amdgcn_s_setprio(1);                                         \
        _Pragma("unroll")                                                      \
        for (int m_ = 0; m_ < 4; ++m_)                                         \
            _Pragma("unroll")                                                  \
            for (int n_ = 0; n_ < 4; ++n_)                                     \
                acc[m_][n_] = __builtin_amdgcn_mfma_f32_16x16x32_bf16(         \
                    af[m_], bfr[n_], acc[m_][n_], 0, 0, 0);                    \
        __builtin_amdgcn_s_setprio(0);                                         \
    } while (0)

// shared transpose tile body (64x64 f32 -> bf16^T), tile points into LDS pool
__device__ inline void transpose_tile(const float* s, bf16* d, int N, int M,
                                      int n0, int m0, float (*tile)[65]) {
    const int tx = threadIdx.x & 15, ty = threadIdx.x >> 4;
#pragma unroll
    for (int i = 0; i < 4; ++i) {
        const int r = ty + i * 16;
        const float4 v = *(const float4*)&s[(size_t)(m0 + r) * N + n0 + tx * 4];
        tile[r][tx * 4 + 0] = v.x;
        tile[r][tx * 4 + 1] = v.y;
        tile[r][tx * 4 + 2] = v.z;
        tile[r][tx * 4 + 3] = v.w;
    }
    __syncthreads();
#pragma unroll
    for (int i = 0; i < 4; ++i) {
        const int nc = ty + i * 16;
        bf16 o[4];
#pragma unroll
        for (int j = 0; j < 4; ++j) o[j] = __float2bfloat16(tile[tx * 4 + j][nc]);
        *(ushort4*)&d[(size_t)(n0 + nc) * M + m0 + tx * 4] = *(const ushort4*)o;
    }
}

// ---- fat dispatch A: W1-transpose (blocks 0..8191) + router+xcvt (8192..10239) ----
__global__ __launch_bounds__(256) void prepA_kernel(
    const float* __restrict__ W1, bf16* __restrict__ W1t,
    const float* __restrict__ x, const float* __restrict__ Wg,
    const float* __restrict__ bg, int* __restrict__ top_idx,
    float* __restrict__ top_gate, bf16* __restrict__ xb) {
    __shared__ alignas(16) char pool[16640];
    const int bid = blockIdx.x;
    if (bid < 8192) {
        const int e = bid >> 10, rem = bid & 1023;
        const int n0 = (rem & 63) * 64, m0 = (rem >> 6) * 64;   // N=F, M=D
        transpose_tile(W1 + (size_t)e * D_DIM * F_DIM,
                       W1t + (size_t)e * D_DIM * F_DIM,
                       F_DIM, D_DIM, n0, m0, (float(*)[65])pool);
        return;
    }
    const int rbid = bid - 8192;
    const int lane = threadIdx.x & 63;
    const int t = rbid * 4 + (threadIdx.x >> 6);
    const float* xrow = x + (size_t)t * D_DIM;

    float acc[E_NUM];
#pragma unroll
    for (int e = 0; e < E_NUM; ++e) acc[e] = 0.f;
#pragma unroll
    for (int it = 0; it < D_DIM / 64; ++it) {
        const int d = it * 64 + lane;
        const float xv = xrow[d];
        const float4 w0 = *(const float4*)&Wg[d * 8];
        const float4 w1 = *(const float4*)&Wg[d * 8 + 4];
        acc[0] += xv * w0.x; acc[1] += xv * w0.y;
        acc[2] += xv * w0.z; acc[3] += xv * w0.w;
        acc[4] += xv * w1.x; acc[5] += xv * w1.y;
        acc[6] += xv * w1.z; acc[7] += xv * w1.w;
    }
#pragma unroll
    for (int off = 32; off > 0; off >>= 1) {
#pragma unroll
        for (int e = 0; e < E_NUM; ++e) acc[e] += __shfl_xor(acc[e], off, 64);
    }
    if (lane == 0) {
        float v[E_NUM];
#pragma unroll
        for (int e = 0; e < E_NUM; ++e) v[e] = acc[e] + bg[e];
        int i0 = 0;
#pragma unroll
        for (int e = 1; e < E_NUM; ++e)
            if (v[e] > v[i0]) i0 = e;
        int i1 = -1;
#pragma unroll
        for (int e = 0; e < E_NUM; ++e) {
            if (e == i0) continue;
            if (i1 < 0 || v[e] > v[i1]) i1 = e;
        }
        const float g0 = 1.f / (1.f + expf(v[i1] - v[i0]));
        top_idx[2 * t] = i0;
        top_idx[2 * t + 1] = i1;
        top_gate[2 * t] = g0;
        top_gate[2 * t + 1] = 1.f - g0;
    }
    const float4* xs = (const float4*)(x + (size_t)rbid * 4 * D_DIM);
    ushort4* xd = (ushort4*)(xb + (size_t)rbid * 4 * D_DIM);
    for (int i = threadIdx.x; i < D_DIM; i += 256) {
        float4 v = xs[i];
        bf16 tmp[4];
        tmp[0] = __float2bfloat16(v.x);
        tmp[1] = __float2bfloat16(v.y);
        tmp[2] = __float2bfloat16(v.z);
        tmp[3] = __float2bfloat16(v.w);
        xd[i] = *(const ushort4*)tmp;
    }
}

// ---- single-block count + padded-prefix offsets, ZERO atomics ----
__global__ __launch_bounds__(256) void count_offsets_kernel(
    const int* __restrict__ top_idx, int* __restrict__ offsets) {
    __shared__ int whist[4][E_NUM];
    int cnt[E_NUM];
#pragma unroll
    for (int e = 0; e < E_NUM; ++e) cnt[e] = 0;
    for (int i = threadIdx.x; i < 2 * T_TOK; i += 256) {
        const int idx = top_idx[i];
#pragma unroll
        for (int e = 0; e < E_NUM; ++e) cnt[e] += (idx == e) ? 1 : 0;
    }
#pragma unroll
    for (int off = 32; off > 0; off >>= 1) {
#pragma unroll
        for (int e = 0; e < E_NUM; ++e) cnt[e] += __shfl_xor(cnt[e], off, 64);
    }
    const int lane = threadIdx.x & 63, w = threadIdx.x >> 6;
    if (lane == 0) {
#pragma unroll
        for (int e = 0; e < E_NUM; ++e) whist[w][e] = cnt[e];
    }
    __syncthreads();
    if (threadIdx.x == 0) {
        int o = 0;
#pragma unroll
        for (int e = 0; e < E_NUM; ++e) {
            const int c = whist[0][e] + whist[1][e] + whist[2][e] + whist[3][e];
            offsets[e] = o;
            o += (c + BM - 1) / BM * BM;
        }
        offsets[E_NUM] = o;
    }
}

// ---- scatter: per-block LDS histogram + one range-reservation atomic per
// (block, expert); also records each token's two slots for the final reduce.
__global__ __launch_bounds__(256) void scatter_kernel(
    const int* __restrict__ top_idx, const float* __restrict__ top_gate,
    const int* __restrict__ offsets, int* __restrict__ cursors,
    int* __restrict__ tok_list, float* __restrict__ gate_list,
    int* __restrict__ tok_slots) {
    __shared__ int lhist[E_NUM];
    __shared__ int lbase[E_NUM];
    if (threadIdx.x < E_NUM) lhist[threadIdx.x] = 0;
    __syncthreads();

    const int t = blockIdx.x * 256 + threadIdx.x;
    int e0 = top_idx[2 * t], e1 = top_idx[2 * t + 1];
    int p0 = atomicAdd(&lhist[e0], 1);
    int p1 = atomicAdd(&lhist[e1], 1);
    __syncthreads();
    if (threadIdx.x < E_NUM)
        lbase[threadIdx.x] = atomicAdd(&cursors[threadIdx.x], lhist[threadIdx.x]);
    __syncthreads();

    const float g0 = top_gate[2 * t], g1 = top_gate[2 * t + 1];
    const int s0 = offsets[e0] + lbase[e0] + p0;
    const int s1 = offsets[e1] + lbase[e1] + p1;
    tok_list[s0] = t;
    gate_list[s0] = g0;
    tok_list[s1] = t;
    gate_list[s1] = g1;
    tok_slots[2 * t] = s0;
    tok_slots[2 * t + 1] = s1;
}

// ---- fat dispatch B: GEMM1 (blocks 0..4351, exact R4) + W2-transpose ----
__global__ __launch_bounds__(256, 4) void gemm1_w2t_kernel(
    const bf16* __restrict__ xb, const bf16* __restrict__ W1t,
    const float* __restrict__ b1, const int* __restrict__ tok_list,
    const int* __restrict__ offsets, bf16* __restrict__ hbuf,
    const float* __restrict__ W2, bf16* __restrict__ W2t) {
    __shared__ alignas(16) char pool[33280];
    if (blockIdx.x >= G1_BLOCKS) {
        const int f2 = blockIdx.x - G1_BLOCKS;
        const int e = f2 >> 10, rem = f2 & 1023;
        const int n0 = (rem & 15) * 64, m0 = (rem >> 4) * 64;   // N=D, M=F
        transpose_tile(W2 + (size_t)e * D_DIM * F_DIM,
                       W2t + (size_t)e * D_DIM * F_DIM,
                       D_DIM, F_DIM, n0, m0, (float(*)[65])pool);
        return;
    }
    bf16* As0 = (bf16*)pool;
    bf16* As1 = (bf16*)(pool + 8192);
    bf16* Bs0 = (bf16*)(pool + 16384);
    bf16* Bs1 = (bf16*)(pool + 24576);
    int* toks = (int*)(pool + 32768);

    const int NCB = F_DIM / 128;          // 32
    const int per = (NUM_RB * NCB) / 8;   // 544
    const int flat = blockIdx.x;
    const int sw = (flat & 7) * per + (flat >> 3);
    const int rb = sw / NCB, cb = sw % NCB;

    const int row0 = rb * BM;
    const int total = offsets[E_NUM];
    if (row0 >= total) return;
    int e = 0;
#pragma unroll
    for (int i = 1; i < E_NUM; ++i) e += (row0 >= offsets[i]) ? 1 : 0;

    const int tid = threadIdx.x;
    if (tid < BM) toks[tid] = tok_list[row0 + tid];
    __syncthreads();   // full drain: vmcnt henceforth counts only stage loads

    const int lane = tid & 63;
    const int w = tid >> 6;
    const int f0 = cb * 128;

    const int r0 = w * 16 + (lane >> 2);
    const int r1 = 64 + w * 16 + (lane >> 2);
    const int c16 = (lane & 3) ^ ((lane >> 3) & 3);
    int t0 = toks[r0]; if (t0 < 0) t0 = 0;
    int t1 = toks[r1]; if (t1 < 0) t1 = 0;
    const bf16* aP0 = xb + (size_t)t0 * D_DIM + c16 * 8;
    const bf16* aP1 = xb + (size_t)t1 * D_DIM + c16 * 8;
    const bf16* bP0 = W1t + ((size_t)e * F_DIM + f0 + r0) * D_DIM + c16 * 8;
    const bf16* bP1 = W1t + ((size_t)e * F_DIM + f0 + r1) * D_DIM + c16 * 8;

    const unsigned dO0 = __builtin_amdgcn_readfirstlane(w * 1024);
    const unsigned dO1 = __builtin_amdgcn_readfirstlane(4096 + w * 1024);

    const int wrow = (w >> 1) * 64, wcol = (w & 1) * 64;
    const int fr = lane & 15;
    const int fkk = 8 * ((lane >> 4) ^ ((lane >> 1) & 3));

    float4v acc[4][4];
#pragma unroll
    for (int m = 0; m < 4; ++m)
#pragma unroll
        for (int n = 0; n < 4; ++n)
#pragma unroll
            for (int r = 0; r < 4; ++r) acc[m][n][r] = 0.f;

    auto stage = [&](int kt, bf16* A, bf16* B) {
        const int ko = kt * 32;
        gl_lds16(aP0 + ko, (bf16*)((char*)A + dO0));
        gl_lds16(aP1 + ko, (bf16*)((char*)A + dO1));
        gl_lds16(bP0 + ko, (bf16*)((char*)B + dO0));
        gl_lds16(bP1 + ko, (bf16*)((char*)B + dO1));
    };

    const int NKT = D_DIM / 32;  // 32
    stage(0, As0, Bs0);
    stage(1, As1, Bs1);
    for (int kt = 0; kt < NKT - 2; kt += 2) {
        PH("vmcnt(4)", As0, Bs0, true, kt + 2);
        PH("vmcnt(4)", As1, Bs1, true, kt + 3);
    }
    PH("vmcnt(4)", As0, Bs0, false, 0);
    PH("vmcnt(0)", As1, Bs1, false, 0);

#pragma unroll
    for (int n = 0; n < 4; ++n) {
        const int gcol = f0 + wcol + n * 16 + fr;
        const float bias = b1[e * F_DIM + gcol];
#pragma unroll
        for (int m = 0; m < 4; ++m) {
#pragma unroll
            for (int r = 0; r < 4; ++r) {
                const int grow = row0 + wrow + m * 16 + (lane >> 4) * 4 + r;
                float v = acc[m][n][r] + bias;
                v = fmaxf(v, 0.f);
                hbuf[(size_t)grow * F_DIM + gcol] = __float2bfloat16(v);
            }
        }
    }
}

// ---------------- GEMM2 (exact R4 loop): y[slot] = gate*(h@W2 + b2) ----------
// Plain coalesced stores instead of 17.8M global atomics; final reduce sums
// each token's two slots.
__global__ __launch_bounds__(256, 4) void gemm2_kernel(
    const bf16* __restrict__ hbuf, const bf16* __restrict__ W2t,
    const float* __restrict__ b2, const int* __restrict__ tok_list,
    const float* __restrict__ gate_list, const int* __restrict__ offsets,
    float* __restrict__ y) {
    __shared__ bf16 As0[BM * 32];
    __shared__ bf16 As1[BM * 32];
    __shared__ bf16 Bs0[BM * 32];
    __shared__ bf16 Bs1[BM * 32];
    __shared__ float gates_s[BM];

    const int NCB = D_DIM / 128;          // 8
    const int per = (NUM_RB * NCB) / 8;   // 136
    const int flat = blockIdx.x;
    const int sw = (flat & 7) * per + (flat >> 3);
    const int rb = sw / NCB, cb = sw % NCB;

    const int row0 = rb * BM;
    const int total = offsets[E_NUM];
    if (row0 >= total) return;
    int e = 0;
#pragma unroll
    for (int i = 1; i < E_NUM; ++i) e += (row0 >= offsets[i]) ? 1 : 0;

    const int tid = threadIdx.x;
    if (tid < BM) {
        int t = tok_list[row0 + tid];
        gates_s[tid] = (t >= 0) ? gate_list[row0 + tid] : 0.f;
    }
    __syncthreads();

    const int lane = tid & 63;
    const int w = tid >> 6;
    const int d0 = cb * 128;

    const int r0 = w * 16 + (lane >> 2);
    const int r1 = 64 + w * 16 + (lane >> 2);
    const int c16 = (lane & 3) ^ ((lane >> 3) & 3);
    const bf16* aP0 = hbuf + (size_t)(row0 + r0) * F_DIM + c16 * 8;
    const bf16* aP1 = hbuf + (size_t)(row0 + r1) * F_DIM + c16 * 8;
    const bf16* bP0 = W2t + ((size_t)e * D_DIM + d0 + r0) * F_DIM + c16 * 8;
    const bf16* bP1 = W2t + ((size_t)e * D_DIM + d0 + r1) * F_DIM + c16 * 8;

    const unsigned dO0 = __builtin_amdgcn_readfirstlane(w * 1024);
    const unsigned dO1 = __builtin_amdgcn_readfirstlane(4096 + w * 1024);

    const int wrow = (w >> 1) * 64, wcol = (w & 1) * 64;
    const int fr = lane & 15;
    const int fkk = 8 * ((lane >> 4) ^ ((lane >> 1) & 3));

    float4v acc[4][4];
#pragma unroll
    for (int m = 0; m < 4; ++m)
#pragma unroll
        for (int n = 0; n < 4; ++n)
#pragma unroll
            for (int r = 0; r < 4; ++r) acc[m][n][r] = 0.f;

    auto stage = [&](int kt, bf16* A, bf16* B) {
        const int ko = kt * 32;
        gl_lds16(aP0 + ko, (bf16*)((char*)A + dO0));
        gl_lds16(aP1 + ko, (bf16*)((char*)A + dO1));
        gl_lds16(bP0 + ko, (bf16*)((char*)B + dO0));
        gl_lds16(bP1 + ko, (bf16*)((char*)B + dO1));
    };

    const int NKT = F_DIM / 32;  // 128
    stage(0, As0, Bs0);
    stage(1, As1, Bs1);
    for (int kt = 0; kt < NKT - 2; kt += 2) {
        PH("vmcnt(4)", As0, Bs0, true, kt + 2);
        PH("vmcnt(4)", As1, Bs1, true, kt + 3);
    }
    PH("vmcnt(4)", As0, Bs0, false, 0);
    PH("vmcnt(0)", As1, Bs1, false, 0);

#pragma unroll
    for (int n = 0; n < 4; ++n) {
        const int gcol = d0 + wcol + n * 16 + fr;
        const float bias = b2[e * D_DIM + gcol];
#pragma unroll
        for (int m = 0; m < 4; ++m) {
#pragma unroll
            for (int r = 0; r < 4; ++r) {
                const int lrow = wrow + m * 16 + (lane >> 4) * 4 + r;
                const float v = (acc[m][n][r] + bias) * gates_s[lrow];
                y[(size_t)(row0 + lrow) * D_DIM + gcol] = v;   // plain store
            }
        }
    }
}

// ---- final reduce: out[t] = y[slot0(t)] + y[slot1(t)] (float4, coalesced) ----
__global__ __launch_bounds__(256) void reduce_kernel(
    const float* __restrict__ y, const int* __restrict__ tok_slots,
    float* __restrict__ out) {
    const int t = blockIdx.x;
    const int s0 = tok_slots[2 * t], s1 = tok_slots[2 * t + 1];
    const float4* y0 = (const float4*)(y + (size_t)s0 * D_DIM);
    const float4* y1 = (const float4*)(y + (size_t)s1 * D_DIM);
    float4* o = (float4*)(out + (size_t)t * D_DIM);
    const int i = threadIdx.x;           // 256 threads x float4 = 1024 ✓
    const float4 a = y0[i], b = y1[i];
    o[i] = make_float4(a.x + b.x, a.y + b.y, a.z + b.z, a.w + b.w);
}

extern "C" void kernel_launch(void* const* d_in, const int* in_sizes, int n_in,
                              void* d_out, int out_size, void* d_ws, size_t ws_size,
                              hipStream_t stream) {
    const float* x = (const float*)d_in[0];
    const float* Wg = (const float*)d_in[1];
    const float* bg = (const float*)d_in[2];
    const float* W1 = (const float*)d_in[3];
    const float* b1 = (const float*)d_in[4];
    const float* W2 = (const float*)d_in[5];
    const float* b2 = (const float*)d_in[6];
    float* out = (float*)d_out;

    char* ws = (char*)d_ws;
    int* cursors = (int*)(ws + 32);     // 8 ints
    int* offsets = (int*)(ws + 64);     // 9 ints
    int* top_idx = (int*)(ws + 256);                     // T*2 ints
    float* top_gate = (float*)(ws + 256 + 65536);        // T*2 floats
    int* tok_list = (int*)(ws + 256 + 2 * 65536);        // MAX_ROWS ints
    float* gate_list = (float*)(ws + 256 + 2 * 65536 + 69632);
    int* tok_slots = (int*)(ws + 270592);                // T*2 ints = 64 KB
    size_t off = 270592 + 65536;                          // 336128
    bf16* xb = (bf16*)(ws + off);                        // 16.8 MB
    float* y = (float*)(ws + off);                       // 71 MB, aliases xb+W1t
    off += (size_t)T_TOK * D_DIM * 2;                    //  (dead after gemm1)
    bf16* W1t = (bf16*)(ws + off);
    off += (size_t)E_NUM * D_DIM * F_DIM * 2;
    bf16* W2t = (bf16*)(ws + off);
    off += (size_t)E_NUM * D_DIM * F_DIM * 2;
    bf16* hbuf = (bf16*)(ws + off);

    hipMemsetAsync(ws, 0, 64, stream);                       // cursors (+pad)
    hipMemsetAsync(tok_list, 0xFF, (size_t)MAX_ROWS * 4, stream);  // -1 sentinels

    prepA_kernel<<<8192 + T_TOK / 4, 256, 0, stream>>>(W1, W1t, x, Wg, bg,
                                                       top_idx, top_gate, xb);
    count_offsets_kernel<<<1, 256, 0, stream>>>(top_idx, offsets);
    scatter_kernel<<<T_TOK / 256, 256, 0, stream>>>(top_idx, top_gate, offsets, cursors,
                                                    tok_list, gate_list, tok_slots);
    gemm1_w2t_kernel<<<G1_BLOCKS + 8192, 256, 0, stream>>>(xb, W1t, b1, tok_list,
                                                           offsets, hbuf, W2, W2t);
    gemm2_kernel<<<NUM_RB * (D_DIM / 128), 256, 0, stream>>>(hbuf, W2t, b2, tok_list,
                                                             gate_list, offsets, y);
    reduce_kernel<<<T_TOK, 256, 0, stream>>>(y, tok_slots, out);
}

// Round 20
// 511.433 us; speedup vs baseline: 2.0093x; 1.0333x over previous
//
#include <hip/hip_runtime.h>
#include <hip/hip_bf16.h>

#define T_TOK 8192
#define D_DIM 1024
#define F_DIM 4096
#define E_NUM 8
#define BM 128
#define MAX_ROWS (2 * T_TOK + E_NUM * BM)   // 17408
#define NUM_RB (MAX_ROWS / BM)              // 136
#define G1_BLOCKS (NUM_RB * (F_DIM / 128))  // 4352

typedef __hip_bfloat16 bf16;
using bf16x8  = __attribute__((ext_vector_type(8))) __bf16;
using float4v = __attribute__((ext_vector_type(4))) float;
using f32x4   = __attribute__((ext_vector_type(4))) float;
using u16x4v  = __attribute__((ext_vector_type(4))) unsigned short;

// async global->LDS, 16B per lane; dest = uniform base + lane*16
__device__ inline void gl_lds16(const bf16* g, bf16* l) {
    __builtin_amdgcn_global_load_lds(
        (const __attribute__((address_space(1))) void*)g,
        (__attribute__((address_space(3))) void*)l, 16, 0, 0);
}

// R4 phase: counted vmcnt, pinned reads, 2 barriers, stage after 2nd barrier.
#define PH(WAITSTR, CA, CB, DOSTAGE, KST)                                      \
    do {                                                                       \
        asm volatile("s_waitcnt " WAITSTR ::: "memory");                       \
        __builtin_amdgcn_s_barrier();                                          \
        bf16x8 af[4], bfr[4];                                                  \
        _Pragma("unroll")                                                      \
        for (int m_ = 0; m_ < 4; ++m_)                                         \
            af[m_] = *(const bf16x8*)&(CA)[(wrow + m_ * 16 + fr) * 32 + fkk];  \
        _Pragma("unroll")                                                      \
        for (int n_ = 0; n_ < 4; ++n_)                                         \
            bfr[n_] = *(const bf16x8*)&(CB)[(wcol + n_ * 16 + fr) * 32 + fkk]; \
        asm volatile("s_waitcnt lgkmcnt(0)" ::: "memory");                     \
        __builtin_amdgcn_sched_barrier(0);                                     \
        __builtin_amdgcn_s_barrier();                                          \
        if (DOSTAGE) stage(KST, CA, CB);                                       \
        __builtin_amdgcn_s_setprio(1);                                         \
        _Pragma("unroll")                                                      \
        for (int m_ = 0; m_ < 4; ++m_)                                         \
            _Pragma("unroll")                                                  \
            for (int n_ = 0; n_ < 4; ++n_)                                     \
                acc[m_][n_] = __builtin_amdgcn_mfma_f32_16x16x32_bf16(         \
                    af[m_], bfr[n_], acc[m_][n_], 0, 0, 0);                    \
        __builtin_amdgcn_s_setprio(0);                                         \
    } while (0)

// shared transpose tile body (64x64 f32 -> bf16^T). NT_LD/NT_ST: non-temporal
// streaming so the 256MB weight pass doesn't evict the concurrent GEMM's
// L2/L3 working set.
template <bool NT_LD, bool NT_ST>
__device__ inline void transpose_tile(const float* s, bf16* d, int N, int M,
                                      int n0, int m0, float (*tile)[65]) {
    const int tx = threadIdx.x & 15, ty = threadIdx.x >> 4;
#pragma unroll
    for (int i = 0; i < 4; ++i) {
        const int r = ty + i * 16;
        const f32x4* sp = (const f32x4*)&s[(size_t)(m0 + r) * N + n0 + tx * 4];
        const f32x4 v = NT_LD ? __builtin_nontemporal_load(sp) : *sp;
        tile[r][tx * 4 + 0] = v[0];
        tile[r][tx * 4 + 1] = v[1];
        tile[r][tx * 4 + 2] = v[2];
        tile[r][tx * 4 + 3] = v[3];
    }
    __syncthreads();
#pragma unroll
    for (int i = 0; i < 4; ++i) {
        const int nc = ty + i * 16;
        u16x4v ov;
#pragma unroll
        for (int j = 0; j < 4; ++j) {
            bf16 b = __float2bfloat16(tile[tx * 4 + j][nc]);
            ov[j] = *(unsigned short*)&b;
        }
        u16x4v* dp = (u16x4v*)&d[(size_t)(n0 + nc) * M + m0 + tx * 4];
        if (NT_ST) __builtin_nontemporal_store(ov, dp);
        else *dp = ov;
    }
    __syncthreads();
}

// ---- fat dispatch A: W1-transpose (blocks 0..8191) + router+xcvt ----
__global__ __launch_bounds__(256) void prepA_kernel(
    const float* __restrict__ W1, bf16* __restrict__ W1t,
    const float* __restrict__ x, const float* __restrict__ Wg,
    const float* __restrict__ bg, int* __restrict__ top_idx,
    float* __restrict__ top_gate, bf16* __restrict__ xb) {
    __shared__ alignas(16) char pool[16640];
    const int bid = blockIdx.x;
    if (bid < 8192) {
        const int e = bid >> 10, rem = bid & 1023;
        const int n0 = (rem & 63) * 64, m0 = (rem >> 6) * 64;   // N=F, M=D
        transpose_tile<true, false>(W1 + (size_t)e * D_DIM * F_DIM,
                                    W1t + (size_t)e * D_DIM * F_DIM,
                                    F_DIM, D_DIM, n0, m0, (float(*)[65])pool);
        return;
    }
    const int rbid = bid - 8192;
    const int lane = threadIdx.x & 63;
    const int t = rbid * 4 + (threadIdx.x >> 6);
    const float* xrow = x + (size_t)t * D_DIM;

    float acc[E_NUM];
#pragma unroll
    for (int e = 0; e < E_NUM; ++e) acc[e] = 0.f;
#pragma unroll
    for (int it = 0; it < D_DIM / 64; ++it) {
        const int d = it * 64 + lane;
        const float xv = xrow[d];
        const float4 w0 = *(const float4*)&Wg[d * 8];
        const float4 w1 = *(const float4*)&Wg[d * 8 + 4];
        acc[0] += xv * w0.x; acc[1] += xv * w0.y;
        acc[2] += xv * w0.z; acc[3] += xv * w0.w;
        acc[4] += xv * w1.x; acc[5] += xv * w1.y;
        acc[6] += xv * w1.z; acc[7] += xv * w1.w;
    }
#pragma unroll
    for (int off = 32; off > 0; off >>= 1) {
#pragma unroll
        for (int e = 0; e < E_NUM; ++e) acc[e] += __shfl_xor(acc[e], off, 64);
    }
    if (lane == 0) {
        float v[E_NUM];
#pragma unroll
        for (int e = 0; e < E_NUM; ++e) v[e] = acc[e] + bg[e];
        int i0 = 0;
#pragma unroll
        for (int e = 1; e < E_NUM; ++e)
            if (v[e] > v[i0]) i0 = e;
        int i1 = -1;
#pragma unroll
        for (int e = 0; e < E_NUM; ++e) {
            if (e == i0) continue;
            if (i1 < 0 || v[e] > v[i1]) i1 = e;
        }
        const float g0 = 1.f / (1.f + expf(v[i1] - v[i0]));
        top_idx[2 * t] = i0;
        top_idx[2 * t + 1] = i1;
        top_gate[2 * t] = g0;
        top_gate[2 * t + 1] = 1.f - g0;
    }
    const float4* xs = (const float4*)(x + (size_t)rbid * 4 * D_DIM);
    ushort4* xd = (ushort4*)(xb + (size_t)rbid * 4 * D_DIM);
    for (int i = threadIdx.x; i < D_DIM; i += 256) {
        float4 v = xs[i];
        bf16 tmp[4];
        tmp[0] = __float2bfloat16(v.x);
        tmp[1] = __float2bfloat16(v.y);
        tmp[2] = __float2bfloat16(v.z);
        tmp[3] = __float2bfloat16(v.w);
        xd[i] = *(const ushort4*)tmp;
    }
}

// ---- scatter with inline recount+offsets (no separate count dispatch) ----
__global__ __launch_bounds__(256) void scatter_kernel(
    const int* __restrict__ top_idx, const float* __restrict__ top_gate,
    int* __restrict__ offsets, int* __restrict__ cursors,
    int* __restrict__ tok_list, float* __restrict__ gate_list,
    int* __restrict__ tok_slots) {
    __shared__ int whist[4][E_NUM];
    __shared__ int offs_s[E_NUM + 1];
    __shared__ int lhist[E_NUM];
    __shared__ int lbase[E_NUM];

    // recount (each block scans all 16K indices; 64KB, L2-hot)
    int cnt[E_NUM];
#pragma unroll
    for (int e = 0; e < E_NUM; ++e) cnt[e] = 0;
    for (int i = threadIdx.x; i < 2 * T_TOK; i += 256) {
        const int idx = top_idx[i];
#pragma unroll
        for (int e = 0; e < E_NUM; ++e) cnt[e] += (idx == e) ? 1 : 0;
    }
#pragma unroll
    for (int off = 32; off > 0; off >>= 1) {
#pragma unroll
        for (int e = 0; e < E_NUM; ++e) cnt[e] += __shfl_xor(cnt[e], off, 64);
    }
    const int lane = threadIdx.x & 63, w = threadIdx.x >> 6;
    if (lane == 0) {
#pragma unroll
        for (int e = 0; e < E_NUM; ++e) whist[w][e] = cnt[e];
    }
    if (threadIdx.x < E_NUM) lhist[threadIdx.x] = 0;
    __syncthreads();
    if (threadIdx.x == 0) {
        int o = 0;
#pragma unroll
        for (int e = 0; e < E_NUM; ++e) {
            const int c = whist[0][e] + whist[1][e] + whist[2][e] + whist[3][e];
            offs_s[e] = o;
            o += (c + BM - 1) / BM * BM;
        }
        offs_s[E_NUM] = o;
    }
    __syncthreads();
    if (blockIdx.x == 0 && threadIdx.x < E_NUM + 1)
        offsets[threadIdx.x] = offs_s[threadIdx.x];

    const int t = blockIdx.x * 256 + threadIdx.x;
    int e0 = top_idx[2 * t], e1 = top_idx[2 * t + 1];
    int p0 = atomicAdd(&lhist[e0], 1);
    int p1 = atomicAdd(&lhist[e1], 1);
    __syncthreads();
    if (threadIdx.x < E_NUM)
        lbase[threadIdx.x] = atomicAdd(&cursors[threadIdx.x], lhist[threadIdx.x]);
    __syncthreads();

    const float g0 = top_gate[2 * t], g1 = top_gate[2 * t + 1];
    const int s0 = offs_s[e0] + lbase[e0] + p0;
    const int s1 = offs_s[e1] + lbase[e1] + p1;
    tok_list[s0] = t;
    gate_list[s0] = g0;
    tok_list[s1] = t;
    gate_list[s1] = g1;
    tok_slots[2 * t] = s0;
    tok_slots[2 * t + 1] = s1;
}

// ---- fat dispatch B: GEMM1 (blocks 0..4351, exact R4) + W2-transpose (nt) ----
__global__ __launch_bounds__(256, 4) void gemm1_w2t_kernel(
    const bf16* __restrict__ xb, const bf16* __restrict__ W1t,
    const float* __restrict__ b1, const int* __restrict__ tok_list,
    const int* __restrict__ offsets, bf16* __restrict__ hbuf,
    const float* __restrict__ W2, bf16* __restrict__ W2t) {
    __shared__ alignas(16) char pool[33280];
    if (blockIdx.x >= G1_BLOCKS) {
        const int f2 = blockIdx.x - G1_BLOCKS;
        const int e = f2 >> 10, rem = f2 & 1023;
        const int n0 = (rem & 15) * 64, m0 = (rem >> 4) * 64;   // N=D, M=F
        transpose_tile<true, true>(W2 + (size_t)e * D_DIM * F_DIM,
                                   W2t + (size_t)e * D_DIM * F_DIM,
                                   D_DIM, F_DIM, n0, m0, (float(*)[65])pool);
        return;
    }
    bf16* As0 = (bf16*)pool;
    bf16* As1 = (bf16*)(pool + 8192);
    bf16* Bs0 = (bf16*)(pool + 16384);
    bf16* Bs1 = (bf16*)(pool + 24576);
    int* toks = (int*)(pool + 32768);

    const int NCB = F_DIM / 128;          // 32
    const int per = (NUM_RB * NCB) / 8;   // 544
    const int flat = blockIdx.x;
    const int sw = (flat & 7) * per + (flat >> 3);
    const int rb = sw / NCB, cb = sw % NCB;

    const int row0 = rb * BM;
    const int total = offsets[E_NUM];
    if (row0 >= total) return;
    int e = 0;
#pragma unroll
    for (int i = 1; i < E_NUM; ++i) e += (row0 >= offsets[i]) ? 1 : 0;

    const int tid = threadIdx.x;
    if (tid < BM) toks[tid] = tok_list[row0 + tid];
    __syncthreads();   // full drain: vmcnt henceforth counts only stage loads

    const int lane = tid & 63;
    const int w = tid >> 6;
    const int f0 = cb * 128;

    const int r0 = w * 16 + (lane >> 2);
    const int r1 = 64 + w * 16 + (lane >> 2);
    const int c16 = (lane & 3) ^ ((lane >> 3) & 3);
    int t0 = toks[r0]; if (t0 < 0) t0 = 0;
    int t1 = toks[r1]; if (t1 < 0) t1 = 0;
    const bf16* aP0 = xb + (size_t)t0 * D_DIM + c16 * 8;
    const bf16* aP1 = xb + (size_t)t1 * D_DIM + c16 * 8;
    const bf16* bP0 = W1t + ((size_t)e * F_DIM + f0 + r0) * D_DIM + c16 * 8;
    const bf16* bP1 = W1t + ((size_t)e * F_DIM + f0 + r1) * D_DIM + c16 * 8;

    const unsigned dO0 = __builtin_amdgcn_readfirstlane(w * 1024);
    const unsigned dO1 = __builtin_amdgcn_readfirstlane(4096 + w * 1024);

    const int wrow = (w >> 1) * 64, wcol = (w & 1) * 64;
    const int fr = lane & 15;
    const int fkk = 8 * ((lane >> 4) ^ ((lane >> 1) & 3));

    float4v acc[4][4];
#pragma unroll
    for (int m = 0; m < 4; ++m)
#pragma unroll
        for (int n = 0; n < 4; ++n)
#pragma unroll
            for (int r = 0; r < 4; ++r) acc[m][n][r] = 0.f;

    auto stage = [&](int kt, bf16* A, bf16* B) {
        const int ko = kt * 32;
        gl_lds16(aP0 + ko, (bf16*)((char*)A + dO0));
        gl_lds16(aP1 + ko, (bf16*)((char*)A + dO1));
        gl_lds16(bP0 + ko, (bf16*)((char*)B + dO0));
        gl_lds16(bP1 + ko, (bf16*)((char*)B + dO1));
    };

    const int NKT = D_DIM / 32;  // 32
    stage(0, As0, Bs0);
    stage(1, As1, Bs1);
    for (int kt = 0; kt < NKT - 2; kt += 2) {
        PH("vmcnt(4)", As0, Bs0, true, kt + 2);
        PH("vmcnt(4)", As1, Bs1, true, kt + 3);
    }
    PH("vmcnt(4)", As0, Bs0, false, 0);
    PH("vmcnt(0)", As1, Bs1, false, 0);

#pragma unroll
    for (int n = 0; n < 4; ++n) {
        const int gcol = f0 + wcol + n * 16 + fr;
        const float bias = b1[e * F_DIM + gcol];
#pragma unroll
        for (int m = 0; m < 4; ++m) {
#pragma unroll
            for (int r = 0; r < 4; ++r) {
                const int grow = row0 + wrow + m * 16 + (lane >> 4) * 4 + r;
                float v = acc[m][n][r] + bias;
                v = fmaxf(v, 0.f);
                hbuf[(size_t)grow * F_DIM + gcol] = __float2bfloat16(v);
            }
        }
    }
}

// ---------------- GEMM2 (exact R4 loop): y[slot] = gate*(h@W2 + b2), bf16 ----
__global__ __launch_bounds__(256, 4) void gemm2_kernel(
    const bf16* __restrict__ hbuf, const bf16* __restrict__ W2t,
    const float* __restrict__ b2, const int* __restrict__ tok_list,
    const float* __restrict__ gate_list, const int* __restrict__ offsets,
    bf16* __restrict__ y) {
    __shared__ bf16 As0[BM * 32];
    __shared__ bf16 As1[BM * 32];
    __shared__ bf16 Bs0[BM * 32];
    __shared__ bf16 Bs1[BM * 32];
    __shared__ float gates_s[BM];

    const int NCB = D_DIM / 128;          // 8
    const int per = (NUM_RB * NCB) / 8;   // 136
    const int flat = blockIdx.x;
    const int sw = (flat & 7) * per + (flat >> 3);
    const int rb = sw / NCB, cb = sw % NCB;

    const int row0 = rb * BM;
    const int total = offsets[E_NUM];
    if (row0 >= total) return;
    int e = 0;
#pragma unroll
    for (int i = 1; i < E_NUM; ++i) e += (row0 >= offsets[i]) ? 1 : 0;

    const int tid = threadIdx.x;
    if (tid < BM) {
        int t = tok_list[row0 + tid];
        gates_s[tid] = (t >= 0) ? gate_list[row0 + tid] : 0.f;
    }
    __syncthreads();

    const int lane = tid & 63;
    const int w = tid >> 6;
    const int d0 = cb * 128;

    const int r0 = w * 16 + (lane >> 2);
    const int r1 = 64 + w * 16 + (lane >> 2);
    const int c16 = (lane & 3) ^ ((lane >> 3) & 3);
    const bf16* aP0 = hbuf + (size_t)(row0 + r0) * F_DIM + c16 * 8;
    const bf16* aP1 = hbuf + (size_t)(row0 + r1) * F_DIM + c16 * 8;
    const bf16* bP0 = W2t + ((size_t)e * D_DIM + d0 + r0) * F_DIM + c16 * 8;
    const bf16* bP1 = W2t + ((size_t)e * D_DIM + d0 + r1) * F_DIM + c16 * 8;

    const unsigned dO0 = __builtin_amdgcn_readfirstlane(w * 1024);
    const unsigned dO1 = __builtin_amdgcn_readfirstlane(4096 + w * 1024);

    const int wrow = (w >> 1) * 64, wcol = (w & 1) * 64;
    const int fr = lane & 15;
    const int fkk = 8 * ((lane >> 4) ^ ((lane >> 1) & 3));

    float4v acc[4][4];
#pragma unroll
    for (int m = 0; m < 4; ++m)
#pragma unroll
        for (int n = 0; n < 4; ++n)
#pragma unroll
            for (int r = 0; r < 4; ++r) acc[m][n][r] = 0.f;

    auto stage = [&](int kt, bf16* A, bf16* B) {
        const int ko = kt * 32;
        gl_lds16(aP0 + ko, (bf16*)((char*)A + dO0));
        gl_lds16(aP1 + ko, (bf16*)((char*)A + dO1));
        gl_lds16(bP0 + ko, (bf16*)((char*)B + dO0));
        gl_lds16(bP1 + ko, (bf16*)((char*)B + dO1));
    };

    const int NKT = F_DIM / 32;  // 128
    stage(0, As0, Bs0);
    stage(1, As1, Bs1);
    for (int kt = 0; kt < NKT - 2; kt += 2) {
        PH("vmcnt(4)", As0, Bs0, true, kt + 2);
        PH("vmcnt(4)", As1, Bs1, true, kt + 3);
    }
    PH("vmcnt(4)", As0, Bs0, false, 0);
    PH("vmcnt(0)", As1, Bs1, false, 0);

#pragma unroll
    for (int n = 0; n < 4; ++n) {
        const int gcol = d0 + wcol + n * 16 + fr;
        const float bias = b2[e * D_DIM + gcol];
#pragma unroll
        for (int m = 0; m < 4; ++m) {
#pragma unroll
            for (int r = 0; r < 4; ++r) {
                const int lrow = wrow + m * 16 + (lane >> 4) * 4 + r;
                const float v = (acc[m][n][r] + bias) * gates_s[lrow];
                y[(size_t)(row0 + lrow) * D_DIM + gcol] = __float2bfloat16(v);
            }
        }
    }
}

// ---- final reduce: out[t] = y[slot0(t)] + y[slot1(t)] (bf16 in, f32 out) ----
__global__ __launch_bounds__(256) void reduce_kernel(
    const bf16* __restrict__ y, const int* __restrict__ tok_slots,
    float* __restrict__ out) {
    const int t = blockIdx.x;
    const int s0 = tok_slots[2 * t], s1 = tok_slots[2 * t + 1];
    const ushort4* y0 = (const ushort4*)(y + (size_t)s0 * D_DIM);
    const ushort4* y1 = (const ushort4*)(y + (size_t)s1 * D_DIM);
    float4* o = (float4*)(out + (size_t)t * D_DIM);
    const int i = threadIdx.x;           // 256 threads x 4 bf16 = 1024 ✓
    const ushort4 a = y0[i], b = y1[i];
    const bf16* ap = (const bf16*)&a;
    const bf16* bp = (const bf16*)&b;
    float4 r;
    r.x = __bfloat162float(ap[0]) + __bfloat162float(bp[0]);
    r.y = __bfloat162float(ap[1]) + __bfloat162float(bp[1]);
    r.z = __bfloat162float(ap[2]) + __bfloat162float(bp[2]);
    r.w = __bfloat162float(ap[3]) + __bfloat162float(bp[3]);
    o[i] = r;
}

extern "C" void kernel_launch(void* const* d_in, const int* in_sizes, int n_in,
                              void* d_out, int out_size, void* d_ws, size_t ws_size,
                              hipStream_t stream) {
    const float* x = (const float*)d_in[0];
    const float* Wg = (const float*)d_in[1];
    const float* bg = (const float*)d_in[2];
    const float* W1 = (const float*)d_in[3];
    const float* b1 = (const float*)d_in[4];
    const float* W2 = (const float*)d_in[5];
    const float* b2 = (const float*)d_in[6];
    float* out = (float*)d_out;

    char* ws = (char*)d_ws;
    int* cursors = (int*)(ws + 32);     // 8 ints
    int* offsets = (int*)(ws + 64);     // 9 ints
    int* top_idx = (int*)(ws + 256);                     // T*2 ints
    float* top_gate = (float*)(ws + 256 + 65536);        // T*2 floats
    int* tok_list = (int*)(ws + 256 + 2 * 65536);        // MAX_ROWS ints
    float* gate_list = (float*)(ws + 256 + 2 * 65536 + 69632);
    int* tok_slots = (int*)(ws + 270592);                // T*2 ints = 64 KB
    size_t off = 270592 + 65536;                          // 336128
    bf16* xb = (bf16*)(ws + off);                        // 16.8 MB
    bf16* y = (bf16*)(ws + off);                         // 35 MB, aliases xb+W1t
    off += (size_t)T_TOK * D_DIM * 2;                    //  (dead after gemm1)
    bf16* W1t = (bf16*)(ws + off);
    off += (size_t)E_NUM * D_DIM * F_DIM * 2;
    bf16* W2t = (bf16*)(ws + off);
    off += (size_t)E_NUM * D_DIM * F_DIM * 2;
    bf16* hbuf = (bf16*)(ws + off);

    hipMemsetAsync(ws, 0, 64, stream);                       // cursors (+pad)
    hipMemsetAsync(tok_list, 0xFF, (size_t)MAX_ROWS * 4, stream);  // -1 sentinels

    prepA_kernel<<<8192 + T_TOK / 4, 256, 0, stream>>>(W1, W1t, x, Wg, bg,
                                                       top_idx, top_gate, xb);
    scatter_kernel<<<T_TOK / 256, 256, 0, stream>>>(top_idx, top_gate, offsets, cursors,
                                                    tok_list, gate_list, tok_slots);
    gemm1_w2t_kernel<<<G1_BLOCKS + 8192, 256, 0, stream>>>(xb, W1t, b1, tok_list,
                                                           offsets, hbuf, W2, W2t);
    gemm2_kernel<<<NUM_RB * (D_DIM / 128), 256, 0, stream>>>(hbuf, W2t, b2, tok_list,
                                                             gate_list, offsets, y);
    reduce_kernel<<<T_TOK, 256, 0, stream>>>(y, tok_slots, out);
}